// Round 3
// baseline (1303.542 us; speedup 1.0000x reference)
//
#include <hip/hip_runtime.h>
#include <math.h>

// Problem constants
#define B_     32
#define F_     64
#define T_     518
#define HID    64
#define GATES  256   // 4*HID
#define CCH    128   // 2*HID lstm output channels
#define NWAVE  6
#define WCH    768   // NWAVE*CCH
#define L2_    516   // T-2   (conv2 out)
#define L3_    512   // L2-4  (conv3 out)
#define L4_    510   // L3-2  (conv4/conv5 out)

__device__ __forceinline__ float frcp(float x) { return __builtin_amdgcn_rcpf(x); }
__device__ __forceinline__ float fsigmoid(float x) { return frcp(1.f + __expf(-x)); }
__device__ __forceinline__ float ftanh(float x) { return 1.f - 2.f * frcp(1.f + __expf(2.f * x)); }

// ---------------------------------------------------------------------------
// K1: xg[b,t,r,gate] = sum_f x[b,f,t]*wih[gate*64+r,f] + bias  (both dirs)
// Gate-interleaved layout so the LSTM reads ONE float4 per lane per step.
// Block (0,0) also zeroes the BN1-stats accumulator (runs well before wave_kernel).
// grid(65, 32), block 256
__global__ void xg_kernel(const float* __restrict__ x,
                          const float* __restrict__ wif, const float* __restrict__ bf,
                          const float* __restrict__ wir, const float* __restrict__ br,
                          float* __restrict__ xg_f, float* __restrict__ xg_r,
                          float* __restrict__ stats) {
    if (blockIdx.x == 0 && blockIdx.y == 0) {
        for (int i = threadIdx.x; i < 2 * WCH; i += 256) stats[i] = 0.f;
    }
    const int g  = threadIdx.x;          // 0..255 : gate row
    const int b  = blockIdx.y;
    const int t0 = blockIdx.x * 8;
    const int r    = g & 63;
    const int gate = g >> 6;
    float4 wa[16], wb[16];
    const float4* w0 = (const float4*)(wif + g * F_);
    const float4* w1 = (const float4*)(wir + g * F_);
#pragma unroll
    for (int i = 0; i < 16; ++i) { wa[i] = w0[i]; wb[i] = w1[i]; }
    const float bfv = bf[g], brv = br[g];
    for (int tt = 0; tt < 8; ++tt) {
        const int t = t0 + tt;
        if (t >= T_) break;
        const float* xp = x + (size_t)b * F_ * T_ + t;
        float a0 = bfv, a1 = brv;
#pragma unroll
        for (int i = 0; i < 16; ++i) {
            float x0 = xp[(i * 4 + 0) * T_];
            float x1 = xp[(i * 4 + 1) * T_];
            float x2 = xp[(i * 4 + 2) * T_];
            float x3 = xp[(i * 4 + 3) * T_];
            a0 += wa[i].x * x0 + wa[i].y * x1 + wa[i].z * x2 + wa[i].w * x3;
            a1 += wb[i].x * x0 + wb[i].y * x1 + wb[i].z * x2 + wb[i].w * x3;
        }
        const size_t o = (((size_t)b * T_ + t) * HID + r) * 4 + gate;
        xg_f[o] = a0;
        xg_r[o] = a1;
    }
}

// ---------------------------------------------------------------------------
// K2: LSTM recurrence — one WAVE per (b,dir). Lane r owns h_r,c_r. Weights in
// VGPR/AGPR. One coalesced float4 xg load per step, depth-2 prefetch so the
// global load has ~2 full steps of slack. No barriers, no explicit waitcnt:
// DS pipe is in-order per wave, compiler inserts fine-grained lgkmcnt.
// grid(64), block 64
__global__ __launch_bounds__(64, 1) void lstm_kernel(
        const float* __restrict__ xgi_f, const float* __restrict__ xgi_r,
        const float* __restrict__ whf, const float* __restrict__ whr,
        float* __restrict__ X) {
    const int dir = blockIdx.x & 1;
    const int b   = blockIdx.x >> 1;
    const float4* xg4 = (const float4*)((dir ? xgi_r : xgi_f) + (size_t)b * T_ * GATES);
    const float* whh = dir ? whr : whf;
    const int r = threadIdx.x;  // 0..63

    float4 wi[16], wf4[16], wg4[16], wo4[16];
    {
        const float4* pi = (const float4*)(whh + (size_t)r * HID);
        const float4* pf = (const float4*)(whh + (size_t)(HID + r) * HID);
        const float4* pg = (const float4*)(whh + (size_t)(2 * HID + r) * HID);
        const float4* po = (const float4*)(whh + (size_t)(3 * HID + r) * HID);
#pragma unroll
        for (int i = 0; i < 16; ++i) { wi[i] = pi[i]; wf4[i] = pf[i]; wg4[i] = pg[i]; wo4[i] = po[i]; }
    }

    __shared__ __align__(16) float hs[HID];
    hs[r] = 0.f;
    float c = 0.f;
    float* Xrow = X + ((size_t)(b * CCH + dir * HID + r)) * T_;

    int t = dir ? (T_ - 1) : 0;
    const int step = dir ? -1 : 1;
    float4 q0 = xg4[(size_t)t * HID + r];
    float4 q1 = xg4[(size_t)(t + step) * HID + r];

    for (int s = 0; s < T_; ++s) {
        // accumulator chains seeded with the xg pre-activation (saves the adds)
        float4 ai = {q0.x, 0.f, 0.f, 0.f};
        float4 af = {q0.y, 0.f, 0.f, 0.f};
        float4 ag = {q0.z, 0.f, 0.f, 0.f};
        float4 ao = {q0.w, 0.f, 0.f, 0.f};
#pragma unroll
        for (int i = 0; i < 16; ++i) {
            float4 h4 = ((const float4*)hs)[i];
            ai.x = fmaf(wi[i].x, h4.x, ai.x);  ai.y = fmaf(wi[i].y, h4.y, ai.y);
            ai.z = fmaf(wi[i].z, h4.z, ai.z);  ai.w = fmaf(wi[i].w, h4.w, ai.w);
            af.x = fmaf(wf4[i].x, h4.x, af.x); af.y = fmaf(wf4[i].y, h4.y, af.y);
            af.z = fmaf(wf4[i].z, h4.z, af.z); af.w = fmaf(wf4[i].w, h4.w, af.w);
            ag.x = fmaf(wg4[i].x, h4.x, ag.x); ag.y = fmaf(wg4[i].y, h4.y, ag.y);
            ag.z = fmaf(wg4[i].z, h4.z, ag.z); ag.w = fmaf(wg4[i].w, h4.w, ag.w);
            ao.x = fmaf(wo4[i].x, h4.x, ao.x); ao.y = fmaf(wo4[i].y, h4.y, ao.y);
            ao.z = fmaf(wo4[i].z, h4.z, ao.z); ao.w = fmaf(wo4[i].w, h4.w, ao.w);
        }
        const float gi = (ai.x + ai.y) + (ai.z + ai.w);
        const float gf = (af.x + af.y) + (af.z + af.w);
        const float gg = (ag.x + ag.y) + (ag.z + ag.w);
        const float go = (ao.x + ao.y) + (ao.z + ao.w);

        // depth-2 prefetch (clamped index; harmless dup loads at the tail)
        int tp = t + 2 * step;
        tp = tp < 0 ? 0 : (tp >= T_ ? T_ - 1 : tp);
        const float4 qn = xg4[(size_t)tp * HID + r];

        const float si = fsigmoid(gi);
        const float sf = fsigmoid(gf);
        const float so = fsigmoid(go);
        c = sf * c + si * ftanh(gg);
        const float h = so * ftanh(c);

        hs[r] = h;       // in-order DS pipe: next iteration's reads see this
        Xrow[t] = h;
        q0 = q1; q1 = qn;
        t += step;
    }
}

// ---------------------------------------------------------------------------
// K3: wave module + fused BN1 partial stats (atomics into `stats`).
// grid(ceil(T/256)=3, 128, 32), block 256
__global__ void wave_kernel(const float* __restrict__ X,
                            const float* __restrict__ bw, const float* __restrict__ bb,
                            float* __restrict__ wave, float* __restrict__ stats) {
    const int b = blockIdx.z, c = blockIdx.y;
    const int t0 = blockIdx.x * 256;
    const int tid = threadIdx.x;
    __shared__ float xs[256 + 14];
    __shared__ float bws[NWAVE][16];
    __shared__ float bbs[NWAVE];
    __shared__ float red[4][12];
    const float* xrow = X + ((size_t)(b * CCH + c)) * T_;
    for (int i = tid; i < 270; i += 256) {
        int tt = t0 - 7 + i;
        xs[i] = (tt >= 0 && tt < T_) ? xrow[tt] : 0.f;
    }
    if (tid < NWAVE * 15) bws[tid / 15][tid % 15] = bw[tid];
    if (tid < NWAVE) bbs[tid] = bb[tid];
    __syncthreads();
    const int t = t0 + tid;
    float ls[NWAVE], lq[NWAVE];
#pragma unroll
    for (int ii = 0; ii < NWAVE; ++ii) { ls[ii] = 0.f; lq[ii] = 0.f; }
    if (t < T_) {
        float win[15];
#pragma unroll
        for (int k = 0; k < 15; ++k) win[k] = xs[tid + k];
        float e[8];
        e[0] = win[7];
#pragma unroll
        for (int m = 1; m < 8; ++m) e[m] = win[7 - m] + win[7 + m];
        const float c0 = 6.28318530717958647692f / 15.f;  // 2*pi/WIDE
#pragma unroll
        for (int ii = 0; ii < NWAVE; ++ii) {
            float sc = bbs[ii];
#pragma unroll
            for (int k = 0; k < 15; ++k) sc += win[k] * bws[ii][k];
            sc = fmaxf(sc, 0.f);
            const float phi = c0 * (float)(ii + 1) * sc;
            float o = e[0];
#pragma unroll
            for (int m = 1; m < 8; ++m) o += e[m] * __cosf(phi * (float)m);
            const float q = (truncf(sc * 15.f) + 1.f) * (2.f / 17.f);
            const float val = o * rsqrtf(q);
            wave[((size_t)(b * WCH + ii * CCH + c)) * T_ + t] = val;
            ls[ii] = val;
            lq[ii] = val * val;
        }
    }
    // block reduction of the 12 partials, then atomics (96 blocks/channel)
#pragma unroll
    for (int off = 32; off > 0; off >>= 1) {
#pragma unroll
        for (int ii = 0; ii < NWAVE; ++ii) {
            ls[ii] += __shfl_down(ls[ii], off);
            lq[ii] += __shfl_down(lq[ii], off);
        }
    }
    if ((tid & 63) == 0) {
        const int w = tid >> 6;
#pragma unroll
        for (int ii = 0; ii < NWAVE; ++ii) { red[w][ii] = ls[ii]; red[w][6 + ii] = lq[ii]; }
    }
    __syncthreads();
    if (tid < 12) {
        const float a = red[0][tid] + red[1][tid] + red[2][tid] + red[3][tid];
        const int ii = tid % 6;
        const int ch = ii * CCH + c;
        atomicAdd(&stats[(tid >= 6 ? WCH : 0) + ch], a);
    }
}

// Finalize BN1 stats: 1 block, 768 threads
__global__ void bn1_finalize_kernel(const float* __restrict__ stats,
                                    float* __restrict__ mean, float* __restrict__ rstd) {
    const int c = threadIdx.x;
    const float n = (float)(B_ * T_);
    const float m = stats[c] / n;
    const float v = stats[WCH + c] / n - m * m;
    mean[c] = m;
    rstd[c] = rsqrtf(v + 1e-5f);
}

// ---------------------------------------------------------------------------
// Generic training-mode BN statistics: one block per channel
__global__ void bn_stats_kernel(const float* __restrict__ x, int Bn, int C, int L,
                                float* __restrict__ mean, float* __restrict__ rstd) {
    const int c = blockIdx.x;
    const int tid = threadIdx.x;
    float s = 0.f, s2 = 0.f;
    for (int b = 0; b < Bn; ++b) {
        const float* row = x + ((size_t)b * C + c) * L;
        for (int l = tid; l < L; l += 256) { float v = row[l]; s += v; s2 += v * v; }
    }
#pragma unroll
    for (int off = 32; off > 0; off >>= 1) { s += __shfl_down(s, off); s2 += __shfl_down(s2, off); }
    __shared__ float ss[4], ss2[4];
    if ((tid & 63) == 0) { ss[tid >> 6] = s; ss2[tid >> 6] = s2; }
    __syncthreads();
    if (tid == 0) {
        float S = ss[0] + ss[1] + ss[2] + ss[3];
        float S2 = ss2[0] + ss2[1] + ss2[2] + ss2[3];
        float n = (float)(Bn * L);
        float m = S / n;
        float v = S2 / n - m * m;
        mean[c] = m;
        rstd[c] = rsqrtf(v + 1e-5f);
    }
}

// In-place BN affine apply, one block per (b,c) row (no per-element int div)
__global__ void bn_apply_row_kernel(float* __restrict__ x, const float* __restrict__ mean,
                                    const float* __restrict__ rstd, const float* __restrict__ g,
                                    const float* __restrict__ be, int C, int L) {
    const int row = blockIdx.x;
    const int c = row % C;
    const float sc = rstd[c] * g[c];
    const float sh = be[c] - mean[c] * sc;
    float* p = x + (size_t)row * L;
    for (int l = threadIdx.x; l < L; l += 256) p[l] = p[l] * sc + sh;
}

// ---------------------------------------------------------------------------
// conv2: [32,768,518] -> relu -> [32,128,516], k=3. grid(3,16,32), block 256
__global__ void conv2_kernel(const float* __restrict__ in, const float* __restrict__ w,
                             const float* __restrict__ bias, float* __restrict__ out) {
    const int t = blockIdx.x * 256 + threadIdx.x;
    const int o0 = blockIdx.y * 8;
    const int b = blockIdx.z;
    if (t >= L2_) return;
    float acc[8];
#pragma unroll
    for (int j = 0; j < 8; ++j) acc[j] = bias[o0 + j];
    const float* inb = in + (size_t)b * WCH * T_ + t;
    const float* wb = w + (size_t)o0 * WCH * 3;
    for (int c = 0; c < WCH; ++c) {
        float x0 = inb[c * T_], x1 = inb[c * T_ + 1], x2 = inb[c * T_ + 2];
        const float* wc = wb + c * 3;
#pragma unroll
        for (int j = 0; j < 8; ++j) {
            const float* wj = wc + (size_t)j * WCH * 3;
            acc[j] += x0 * wj[0] + x1 * wj[1] + x2 * wj[2];
        }
    }
    const size_t ob = ((size_t)b * 128 + o0) * L2_ + t;
#pragma unroll
    for (int j = 0; j < 8; ++j) out[ob + (size_t)j * L2_] = fmaxf(acc[j], 0.f);
}

// conv3: [32,128,516] -> relu -> [32,32,512], k=5. grid(2,4,32), block 256
__global__ void conv3_kernel(const float* __restrict__ in, const float* __restrict__ w,
                             const float* __restrict__ bias, float* __restrict__ out) {
    const int t = blockIdx.x * 256 + threadIdx.x;
    const int o0 = blockIdx.y * 8;
    const int b = blockIdx.z;
    if (t >= L3_) return;
    float acc[8];
#pragma unroll
    for (int j = 0; j < 8; ++j) acc[j] = bias[o0 + j];
    const float* inb = in + (size_t)b * 128 * L2_ + t;
    const float* wb = w + (size_t)o0 * 128 * 5;
    for (int c = 0; c < 128; ++c) {
        float x0 = inb[c * L2_], x1 = inb[c * L2_ + 1], x2 = inb[c * L2_ + 2];
        float x3 = inb[c * L2_ + 3], x4 = inb[c * L2_ + 4];
        const float* wc = wb + c * 5;
#pragma unroll
        for (int j = 0; j < 8; ++j) {
            const float* wj = wc + (size_t)j * 128 * 5;
            acc[j] += x0 * wj[0] + x1 * wj[1] + x2 * wj[2] + x3 * wj[3] + x4 * wj[4];
        }
    }
    const size_t ob = ((size_t)b * 32 + o0) * L3_ + t;
#pragma unroll
    for (int j = 0; j < 8; ++j) out[ob + (size_t)j * L3_] = fmaxf(acc[j], 0.f);
}

// conv4: [32,32,512] -> relu -> [32,16,510], k=3. grid(2,16,32), block 256
__global__ void conv4_kernel(const float* __restrict__ in, const float* __restrict__ w,
                             const float* __restrict__ bias, float* __restrict__ out) {
    const int t = blockIdx.x * 256 + threadIdx.x;
    const int o = blockIdx.y;
    const int b = blockIdx.z;
    if (t >= L4_) return;
    float acc = bias[o];
    const float* inb = in + (size_t)b * 32 * L3_ + t;
    const float* wo = w + (size_t)o * 32 * 3;
    for (int c = 0; c < 32; ++c) {
        acc += inb[c * L3_] * wo[c * 3] + inb[c * L3_ + 1] * wo[c * 3 + 1] +
               inb[c * L3_ + 2] * wo[c * 3 + 2];
    }
    out[((size_t)b * 16 + o) * L4_ + t] = fmaxf(acc, 0.f);
}

// Fused DWT bands + conv5 + relu -> y5 [32,16,510]. grid(32), block 512
__global__ __launch_bounds__(512) void dwt_conv5_kernel(const float* __restrict__ y3,
                                                        const float* __restrict__ w5,
                                                        const float* __restrict__ b5,
                                                        float* __restrict__ y5) {
    const int b = blockIdx.x, l = threadIdx.x;  // l in [0,512)
    __shared__ float cm[L3_];
    __shared__ float bands[5][L3_];
    __shared__ float w5s[240];
    __shared__ float b5s[16];
    float s = 0.f;
    for (int ch = 0; ch < 32; ++ch) s += y3[((size_t)b * 32 + ch) * L3_ + l];
    cm[l] = s * (1.f / 32.f);
    if (l < 240) w5s[l] = w5[l];
    if (l < 16) b5s[l] = b5[l];
    __syncthreads();
    const float s1 = 0.70710678118654752440f;
    const float s2c = 0.5f;
    const float s3 = 0.35355339059327378f;
    const float s4 = 0.25f;
    const int b16 = l & ~15, b8 = l & ~7, b4v = l & ~3, b2v = l & ~1;
    float sa = 0.f, sb = 0.f;
#pragma unroll
    for (int i = 0; i < 8; ++i) { sa += cm[b16 + i]; sb += cm[b16 + 8 + i]; }
    bands[0][l] = (sa + sb) * s4;
    bands[1][l] = (sa - sb) * s4;
    float ta = 0.f, tb = 0.f;
#pragma unroll
    for (int i = 0; i < 4; ++i) { ta += cm[b8 + i]; tb += cm[b8 + 4 + i]; }
    bands[2][l] = (ta - tb) * s3;
    bands[3][l] = (cm[b4v] + cm[b4v + 1] - cm[b4v + 2] - cm[b4v + 3]) * s2c;
    bands[4][l] = (cm[b2v] - cm[b2v + 1]) * s1;
    __syncthreads();
    if (l < L4_) {
        float in3[5][3];
#pragma unroll
        for (int c = 0; c < 5; ++c) {
            in3[c][0] = bands[c][l]; in3[c][1] = bands[c][l + 1]; in3[c][2] = bands[c][l + 2];
        }
#pragma unroll
        for (int o = 0; o < 16; ++o) {
            float acc = b5s[o];
#pragma unroll
            for (int c = 0; c < 5; ++c) {
                const float* wp = &w5s[(o * 5 + c) * 3];
                acc += in3[c][0] * wp[0] + in3[c][1] * wp[1] + in3[c][2] * wp[2];
            }
            y5[((size_t)b * 16 + o) * L4_ + l] = fmaxf(acc, 0.f);
        }
    }
}

// Merged BN4-stats + BN5-stats + pooling + FC. grid(1), block 512.
// thread p = b*16+ch owns row sums; then per-channel reduce; then FC.
__global__ __launch_bounds__(512) void tail_final_kernel(
        const float* __restrict__ y4, const float* __restrict__ y5,
        const float* __restrict__ g4, const float* __restrict__ be4,
        const float* __restrict__ g5, const float* __restrict__ be5,
        const float* __restrict__ fcw, const float* __restrict__ fcb,
        float* __restrict__ out) {
    const int p = threadIdx.x;           // 0..511
    const int b = p >> 4, ch = p & 15;
    const float2* p4 = (const float2*)(y4 + ((size_t)(b * 16 + ch)) * L4_);
    const float2* p5 = (const float2*)(y5 + ((size_t)(b * 16 + ch)) * L4_);
    float s4 = 0.f, q4 = 0.f, s5 = 0.f, q5 = 0.f;
    for (int i = 0; i < L4_ / 2; ++i) {
        float2 a = p4[i], bb2 = p5[i];
        s4 += a.x + a.y;  q4 += a.x * a.x + a.y * a.y;
        s5 += bb2.x + bb2.y; q5 += bb2.x * bb2.x + bb2.y * bb2.y;
    }
    __shared__ float S4[512], Q4[512], S5[512], Q5[512];
    __shared__ float M4[16], R4[16], M5[16], R5[16];
    __shared__ float pool[B_][16];
    S4[p] = s4; Q4[p] = q4; S5[p] = s5; Q5[p] = q5;
    __syncthreads();
    if (p < 16) {
        float ts = 0.f, tq = 0.f, us = 0.f, uq = 0.f;
        for (int bb = 0; bb < B_; ++bb) {
            ts += S4[bb * 16 + p]; tq += Q4[bb * 16 + p];
            us += S5[bb * 16 + p]; uq += Q5[bb * 16 + p];
        }
        const float n = (float)(B_ * L4_);
        float m = ts / n; M4[p] = m; R4[p] = rsqrtf(tq / n - m * m + 1e-5f);
        m = us / n;       M5[p] = m; R5[p] = rsqrtf(uq / n - m * m + 1e-5f);
    }
    __syncthreads();
    {
        const float mm4 = s4 / (float)L4_, mm5 = s5 / (float)L4_;
        const float v4 = (mm4 - M4[ch]) * R4[ch] * g4[ch] + be4[ch];
        const float v5 = (mm5 - M5[ch]) * R5[ch] * g5[ch] + be5[ch];
        pool[b][ch] = 0.5f * (v4 + v5);
    }
    __syncthreads();
    if (p < B_ * 10) {
        const int bb = p / 10, row = p - bb * 10;
        float a = fcb[row];
#pragma unroll
        for (int c = 0; c < 16; ++c) a += pool[bb][c] * fcw[row * 16 + c];
        out[bb * 10 + row] = a;
    }
}

// ---------------------------------------------------------------------------
extern "C" void kernel_launch(void* const* d_in, const int* in_sizes, int n_in,
                              void* d_out, int out_size, void* d_ws, size_t ws_size,
                              hipStream_t stream) {
    (void)in_sizes; (void)n_in; (void)out_size; (void)ws_size;
    const float* x   = (const float*)d_in[0];
    const float* wif = (const float*)d_in[1];
    const float* whf = (const float*)d_in[2];
    const float* bf  = (const float*)d_in[3];
    const float* wir = (const float*)d_in[4];
    const float* whr = (const float*)d_in[5];
    const float* br  = (const float*)d_in[6];
    const float* bw  = (const float*)d_in[7];
    const float* bb  = (const float*)d_in[8];
    const float* g1  = (const float*)d_in[9];  const float* be1 = (const float*)d_in[10];
    const float* g2  = (const float*)d_in[11]; const float* be2 = (const float*)d_in[12];
    const float* g3  = (const float*)d_in[13]; const float* be3 = (const float*)d_in[14];
    const float* g4  = (const float*)d_in[15]; const float* be4 = (const float*)d_in[16];
    const float* g5  = (const float*)d_in[17]; const float* be5 = (const float*)d_in[18];
    const float* w2  = (const float*)d_in[19]; const float* b2  = (const float*)d_in[20];
    const float* w3  = (const float*)d_in[21]; const float* b3  = (const float*)d_in[22];
    const float* w4  = (const float*)d_in[23]; const float* b4  = (const float*)d_in[24];
    const float* w5  = (const float*)d_in[25]; const float* b5  = (const float*)d_in[26];
    const float* fcw = (const float*)d_in[27]; const float* fcb = (const float*)d_in[28];
    float* out = (float*)d_out;
    float* ws  = (float*)d_ws;

    // Workspace layout (floats). xg region is reused by `wave` after the LSTM.
    float* xg_f  = ws;                       //  4,243,456
    float* xg_r  = ws + 4243456;             //  4,243,456
    float* wave  = ws;                       // 12,730,368 (reuses xg region)
    float* X     = ws + 12730368;            //  2,121,728
    float* y2    = ws + 14852096;            //  2,113,536
    float* y3    = ws + 16965632;            //    524,288
    float* y4    = ws + 17489920;            //    261,120
    float* y5    = ws + 17751040;            //    261,120
    float* stats = ws + 18012160;            //      1,536 (BN1 s/s2)
    float* m1 = ws + 18013696; float* r1 = m1 + 768;
    float* m2 = r1 + 768;      float* r2 = m2 + 128;
    float* m3 = r2 + 128;      float* r3 = m3 + 32;   // ends ~18,015,296 floats

    // 1) input projections (gate-interleaved layout) + zero BN1 stats
    xg_kernel<<<dim3(65, 32), 256, 0, stream>>>(x, wif, bf, wir, br, xg_f, xg_r, stats);
    // 2) bidirectional LSTM recurrence -> X [32,128,518]  (one wave per chain)
    lstm_kernel<<<dim3(64), 64, 0, stream>>>(xg_f, xg_r, whf, whr, X);
    // 3) wave module -> wave [32,768,518], fused BN1 partial stats
    wave_kernel<<<dim3(3, CCH, B_), 256, 0, stream>>>(X, bw, bb, wave, stats);
    bn1_finalize_kernel<<<dim3(1), 768, 0, stream>>>(stats, m1, r1);
    bn_apply_row_kernel<<<dim3(B_ * WCH), 256, 0, stream>>>(wave, m1, r1, g1, be1, WCH, T_);
    // 5) conv2 + relu -> y2; BN2
    conv2_kernel<<<dim3(3, 16, B_), 256, 0, stream>>>(wave, w2, b2, y2);
    bn_stats_kernel<<<dim3(128), 256, 0, stream>>>(y2, B_, 128, L2_, m2, r2);
    bn_apply_row_kernel<<<dim3(B_ * 128), 256, 0, stream>>>(y2, m2, r2, g2, be2, 128, L2_);
    // 6) conv3 + relu -> y3; BN3
    conv3_kernel<<<dim3(2, 4, B_), 256, 0, stream>>>(y2, w3, b3, y3);
    bn_stats_kernel<<<dim3(32), 256, 0, stream>>>(y3, B_, 32, L3_, m3, r3);
    bn_apply_row_kernel<<<dim3(B_ * 32), 256, 0, stream>>>(y3, m3, r3, g3, be3, 32, L3_);
    // 7) conv4 + relu -> y4
    conv4_kernel<<<dim3(2, 16, B_), 256, 0, stream>>>(y3, w4, b4, y4);
    // 8) fused DWT + conv5 + relu -> y5
    dwt_conv5_kernel<<<dim3(B_), 512, 0, stream>>>(y3, w5, b5, y5);
    // 9) merged BN4/BN5 stats + pooling(+affine) + FC -> out [32,10]
    tail_final_kernel<<<dim3(1), 512, 0, stream>>>(y4, y5, g4, be4, g5, be5, fcw, fcb, out);
}

// Round 4
// 1200.904 us; speedup vs baseline: 1.0855x; 1.0855x over previous
//
#include <hip/hip_runtime.h>
#include <math.h>

// Problem constants
#define B_     32
#define F_     64
#define T_     518
#define HID    64
#define GATES  256   // 4*HID
#define CCH    128   // 2*HID lstm output channels
#define NWAVE  6
#define WCH    768   // NWAVE*CCH
#define L2_    516   // T-2   (conv2 out)
#define L3_    512   // L2-4  (conv3 out)
#define L4_    510   // L3-2  (conv4/conv5 out)

typedef float v2f __attribute__((ext_vector_type(2)));

__device__ __forceinline__ float frcp(float x) { return __builtin_amdgcn_rcpf(x); }
__device__ __forceinline__ float fsigmoid(float x) { return frcp(1.f + __expf(-x)); }
__device__ __forceinline__ float ftanh(float x) { return 1.f - 2.f * frcp(1.f + __expf(2.f * x)); }

#if __has_builtin(__builtin_elementwise_fma)
__device__ __forceinline__ v2f pk_fma(v2f a, v2f b, v2f c) { return __builtin_elementwise_fma(a, b, c); }
#else
__device__ __forceinline__ v2f pk_fma(v2f a, v2f b, v2f c) {
    v2f r; r.x = fmaf(a.x, b.x, c.x); r.y = fmaf(a.y, b.y, c.y); return r;
}
#endif

// ---------------------------------------------------------------------------
// K1: xg[b,t,r,gate] = sum_f x[b,f,t]*wih[gate*64+r,f] + bias  (both dirs)
// Thread->gate-row mapping permuted so the interleaved store is base+tid
// (fully coalesced). Block (0,0) also zeroes the BN1-stats accumulator.
// grid(65, 32), block 256
__global__ void xg_kernel(const float* __restrict__ x,
                          const float* __restrict__ wif, const float* __restrict__ bf,
                          const float* __restrict__ wir, const float* __restrict__ br,
                          float* __restrict__ xg_f, float* __restrict__ xg_r,
                          float* __restrict__ stats) {
    if (blockIdx.x == 0 && blockIdx.y == 0) {
        for (int i = threadIdx.x; i < 2 * WCH; i += 256) stats[i] = 0.f;
    }
    const int tid = threadIdx.x;
    const int g   = (tid & 3) * 64 + (tid >> 2);   // gate row; store offset == tid
    const int b   = blockIdx.y;
    const int t0  = blockIdx.x * 8;
    float4 wa[16], wb[16];
    const float4* w0 = (const float4*)(wif + g * F_);
    const float4* w1 = (const float4*)(wir + g * F_);
#pragma unroll
    for (int i = 0; i < 16; ++i) { wa[i] = w0[i]; wb[i] = w1[i]; }
    const float bfv = bf[g], brv = br[g];
    for (int tt = 0; tt < 8; ++tt) {
        const int t = t0 + tt;
        if (t >= T_) break;
        const float* xp = x + (size_t)b * F_ * T_ + t;
        float a0 = bfv, a1 = brv;
#pragma unroll
        for (int i = 0; i < 16; ++i) {
            float x0 = xp[(i * 4 + 0) * T_];
            float x1 = xp[(i * 4 + 1) * T_];
            float x2 = xp[(i * 4 + 2) * T_];
            float x3 = xp[(i * 4 + 3) * T_];
            a0 += wa[i].x * x0 + wa[i].y * x1 + wa[i].z * x2 + wa[i].w * x3;
            a1 += wb[i].x * x0 + wb[i].y * x1 + wb[i].z * x2 + wb[i].w * x3;
        }
        const size_t o = ((size_t)b * T_ + t) * GATES + tid;   // coalesced
        xg_f[o] = a0;
        xg_r[o] = a1;
    }
}

// ---------------------------------------------------------------------------
// K2: LSTM recurrence — one WAVE per (b,dir). Lane r owns h_r,c_r. Weights
// held in 256 VGPRs as v2f pairs; packed v_pk_fma_f32 halves the FMA issue
// count. The empty asm+memory clobber per iteration pins the weight loads
// above the loop (prevents rematerialization — R2's VGPR 168 regression) and
// orders the hs[] write before next iteration's reads. One coalesced float4
// xg load per step, depth-2 prefetch. grid(64), block 64.
__global__ __launch_bounds__(64, 1) void lstm_kernel(
        const float* __restrict__ xgi_f, const float* __restrict__ xgi_r,
        const float* __restrict__ whf, const float* __restrict__ whr,
        float* __restrict__ X) {
    const int dir = blockIdx.x & 1;
    const int b   = blockIdx.x >> 1;
    const float4* xg4 = (const float4*)((dir ? xgi_r : xgi_f) + (size_t)b * T_ * GATES);
    const float* whh = dir ? whr : whf;
    const int r = threadIdx.x;  // 0..63

    v2f wi2[32], wf2[32], wg2[32], wo2[32];
    {
        const v2f* pi = (const v2f*)(whh + (size_t)r * HID);
        const v2f* pf = (const v2f*)(whh + (size_t)(HID + r) * HID);
        const v2f* pg = (const v2f*)(whh + (size_t)(2 * HID + r) * HID);
        const v2f* po = (const v2f*)(whh + (size_t)(3 * HID + r) * HID);
#pragma unroll
        for (int i = 0; i < 32; ++i) { wi2[i] = pi[i]; wf2[i] = pf[i]; wg2[i] = pg[i]; wo2[i] = po[i]; }
    }

    __shared__ __align__(16) float hs[HID];
    hs[r] = 0.f;
    float c = 0.f;
    float* Xrow = X + ((size_t)(b * CCH + dir * HID + r)) * T_;

    int t = dir ? (T_ - 1) : 0;
    const int step = dir ? -1 : 1;
    float4 q0 = xg4[(size_t)t * HID + r];
    float4 q1 = xg4[(size_t)(t + step) * HID + r];

    for (int s = 0; s < T_; ++s) {
        v2f aiL = {q0.x, 0.f}, aiH = {0.f, 0.f};
        v2f afL = {q0.y, 0.f}, afH = {0.f, 0.f};
        v2f agL = {q0.z, 0.f}, agH = {0.f, 0.f};
        v2f aoL = {q0.w, 0.f}, aoH = {0.f, 0.f};
#pragma unroll
        for (int i = 0; i < 16; ++i) {
            const float4 h4 = ((const float4*)hs)[i];
            const v2f hL = {h4.x, h4.y};
            const v2f hH = {h4.z, h4.w};
            aiL = pk_fma(wi2[2 * i], hL, aiL); aiH = pk_fma(wi2[2 * i + 1], hH, aiH);
            afL = pk_fma(wf2[2 * i], hL, afL); afH = pk_fma(wf2[2 * i + 1], hH, afH);
            agL = pk_fma(wg2[2 * i], hL, agL); agH = pk_fma(wg2[2 * i + 1], hH, agH);
            aoL = pk_fma(wo2[2 * i], hL, aoL); aoH = pk_fma(wo2[2 * i + 1], hH, aoH);
        }
        const float gi = (aiL.x + aiL.y) + (aiH.x + aiH.y);
        const float gf = (afL.x + afL.y) + (afH.x + afH.y);
        const float gg = (agL.x + agL.y) + (agH.x + agH.y);
        const float go = (aoL.x + aoL.y) + (aoH.x + aoH.y);

        // depth-2 prefetch (clamped index; harmless dup loads at the tail)
        int tp = t + 2 * step;
        tp = tp < 0 ? 0 : (tp >= T_ ? T_ - 1 : tp);
        const float4 qn = xg4[(size_t)tp * HID + r];

        const float si = fsigmoid(gi);
        const float sf = fsigmoid(gf);
        const float so = fsigmoid(go);
        c = sf * c + si * ftanh(gg);
        const float h = so * ftanh(c);

        hs[r] = h;       // in-order DS pipe: next iteration's reads see this
        Xrow[t] = h;
        // Pin weight loads above the loop + order hs write vs next reads.
        asm volatile("" ::: "memory");
        q0 = q1; q1 = qn;
        t += step;
    }
}

// ---------------------------------------------------------------------------
// K3: wave module + fused BN1 partial stats (atomics into `stats`).
// grid(ceil(T/256)=3, 128, 32), block 256
__global__ void wave_kernel(const float* __restrict__ X,
                            const float* __restrict__ bw, const float* __restrict__ bb,
                            float* __restrict__ wave, float* __restrict__ stats) {
    const int b = blockIdx.z, c = blockIdx.y;
    const int t0 = blockIdx.x * 256;
    const int tid = threadIdx.x;
    __shared__ float xs[256 + 14];
    __shared__ float bws[NWAVE][16];
    __shared__ float bbs[NWAVE];
    __shared__ float red[4][12];
    const float* xrow = X + ((size_t)(b * CCH + c)) * T_;
    for (int i = tid; i < 270; i += 256) {
        int tt = t0 - 7 + i;
        xs[i] = (tt >= 0 && tt < T_) ? xrow[tt] : 0.f;
    }
    if (tid < NWAVE * 15) bws[tid / 15][tid % 15] = bw[tid];
    if (tid < NWAVE) bbs[tid] = bb[tid];
    __syncthreads();
    const int t = t0 + tid;
    float ls[NWAVE], lq[NWAVE];
#pragma unroll
    for (int ii = 0; ii < NWAVE; ++ii) { ls[ii] = 0.f; lq[ii] = 0.f; }
    if (t < T_) {
        float win[15];
#pragma unroll
        for (int k = 0; k < 15; ++k) win[k] = xs[tid + k];
        float e[8];
        e[0] = win[7];
#pragma unroll
        for (int m = 1; m < 8; ++m) e[m] = win[7 - m] + win[7 + m];
        const float c0 = 6.28318530717958647692f / 15.f;  // 2*pi/WIDE
#pragma unroll
        for (int ii = 0; ii < NWAVE; ++ii) {
            float sc = bbs[ii];
#pragma unroll
            for (int k = 0; k < 15; ++k) sc += win[k] * bws[ii][k];
            sc = fmaxf(sc, 0.f);
            const float phi = c0 * (float)(ii + 1) * sc;
            float o = e[0];
#pragma unroll
            for (int m = 1; m < 8; ++m) o += e[m] * __cosf(phi * (float)m);
            const float q = (truncf(sc * 15.f) + 1.f) * (2.f / 17.f);
            const float val = o * rsqrtf(q);
            wave[((size_t)(b * WCH + ii * CCH + c)) * T_ + t] = val;
            ls[ii] = val;
            lq[ii] = val * val;
        }
    }
    // block reduction of the 12 partials, then atomics (96 blocks/channel)
#pragma unroll
    for (int off = 32; off > 0; off >>= 1) {
#pragma unroll
        for (int ii = 0; ii < NWAVE; ++ii) {
            ls[ii] += __shfl_down(ls[ii], off);
            lq[ii] += __shfl_down(lq[ii], off);
        }
    }
    if ((tid & 63) == 0) {
        const int w = tid >> 6;
#pragma unroll
        for (int ii = 0; ii < NWAVE; ++ii) { red[w][ii] = ls[ii]; red[w][6 + ii] = lq[ii]; }
    }
    __syncthreads();
    if (tid < 12) {
        const float a = red[0][tid] + red[1][tid] + red[2][tid] + red[3][tid];
        const int ii = tid % 6;
        const int ch = ii * CCH + c;
        atomicAdd(&stats[(tid >= 6 ? WCH : 0) + ch], a);
    }
}

// Finalize BN1 stats: 1 block, 768 threads
__global__ void bn1_finalize_kernel(const float* __restrict__ stats,
                                    float* __restrict__ mean, float* __restrict__ rstd) {
    const int c = threadIdx.x;
    const float n = (float)(B_ * T_);
    const float m = stats[c] / n;
    const float v = stats[WCH + c] / n - m * m;
    mean[c] = m;
    rstd[c] = rsqrtf(v + 1e-5f);
}

// ---------------------------------------------------------------------------
// Generic training-mode BN statistics: one block per channel
__global__ void bn_stats_kernel(const float* __restrict__ x, int Bn, int C, int L,
                                float* __restrict__ mean, float* __restrict__ rstd) {
    const int c = blockIdx.x;
    const int tid = threadIdx.x;
    float s = 0.f, s2 = 0.f;
    for (int b = 0; b < Bn; ++b) {
        const float* row = x + ((size_t)b * C + c) * L;
        for (int l = tid; l < L; l += 256) { float v = row[l]; s += v; s2 += v * v; }
    }
#pragma unroll
    for (int off = 32; off > 0; off >>= 1) { s += __shfl_down(s, off); s2 += __shfl_down(s2, off); }
    __shared__ float ss[4], ss2[4];
    if ((tid & 63) == 0) { ss[tid >> 6] = s; ss2[tid >> 6] = s2; }
    __syncthreads();
    if (tid == 0) {
        float S = ss[0] + ss[1] + ss[2] + ss[3];
        float S2 = ss2[0] + ss2[1] + ss2[2] + ss2[3];
        float n = (float)(Bn * L);
        float m = S / n;
        float v = S2 / n - m * m;
        mean[c] = m;
        rstd[c] = rsqrtf(v + 1e-5f);
    }
}

// In-place BN affine apply, one block per (b,c) row (no per-element int div)
__global__ void bn_apply_row_kernel(float* __restrict__ x, const float* __restrict__ mean,
                                    const float* __restrict__ rstd, const float* __restrict__ g,
                                    const float* __restrict__ be, int C, int L) {
    const int row = blockIdx.x;
    const int c = row % C;
    const float sc = rstd[c] * g[c];
    const float sh = be[c] - mean[c] * sc;
    float* p = x + (size_t)row * L;
    for (int l = threadIdx.x; l < L; l += 256) p[l] = p[l] * sc + sh;
}

// ---------------------------------------------------------------------------
// conv2: [32,768,518] -> relu -> [32,128,516], k=3. grid(3,16,32), block 256
__global__ void conv2_kernel(const float* __restrict__ in, const float* __restrict__ w,
                             const float* __restrict__ bias, float* __restrict__ out) {
    const int t = blockIdx.x * 256 + threadIdx.x;
    const int o0 = blockIdx.y * 8;
    const int b = blockIdx.z;
    if (t >= L2_) return;
    float acc[8];
#pragma unroll
    for (int j = 0; j < 8; ++j) acc[j] = bias[o0 + j];
    const float* inb = in + (size_t)b * WCH * T_ + t;
    const float* wb = w + (size_t)o0 * WCH * 3;
    for (int c = 0; c < WCH; ++c) {
        float x0 = inb[c * T_], x1 = inb[c * T_ + 1], x2 = inb[c * T_ + 2];
        const float* wc = wb + c * 3;
#pragma unroll
        for (int j = 0; j < 8; ++j) {
            const float* wj = wc + (size_t)j * WCH * 3;
            acc[j] += x0 * wj[0] + x1 * wj[1] + x2 * wj[2];
        }
    }
    const size_t ob = ((size_t)b * 128 + o0) * L2_ + t;
#pragma unroll
    for (int j = 0; j < 8; ++j) out[ob + (size_t)j * L2_] = fmaxf(acc[j], 0.f);
}

// conv3: [32,128,516] -> relu -> [32,32,512], k=5. grid(2,4,32), block 256
__global__ void conv3_kernel(const float* __restrict__ in, const float* __restrict__ w,
                             const float* __restrict__ bias, float* __restrict__ out) {
    const int t = blockIdx.x * 256 + threadIdx.x;
    const int o0 = blockIdx.y * 8;
    const int b = blockIdx.z;
    if (t >= L3_) return;
    float acc[8];
#pragma unroll
    for (int j = 0; j < 8; ++j) acc[j] = bias[o0 + j];
    const float* inb = in + (size_t)b * 128 * L2_ + t;
    const float* wb = w + (size_t)o0 * 128 * 5;
    for (int c = 0; c < 128; ++c) {
        float x0 = inb[c * L2_], x1 = inb[c * L2_ + 1], x2 = inb[c * L2_ + 2];
        float x3 = inb[c * L2_ + 3], x4 = inb[c * L2_ + 4];
        const float* wc = wb + c * 5;
#pragma unroll
        for (int j = 0; j < 8; ++j) {
            const float* wj = wc + (size_t)j * 128 * 5;
            acc[j] += x0 * wj[0] + x1 * wj[1] + x2 * wj[2] + x3 * wj[3] + x4 * wj[4];
        }
    }
    const size_t ob = ((size_t)b * 32 + o0) * L3_ + t;
#pragma unroll
    for (int j = 0; j < 8; ++j) out[ob + (size_t)j * L3_] = fmaxf(acc[j], 0.f);
}

// conv4: [32,32,512] -> relu -> [32,16,510], k=3. grid(2,16,32), block 256
__global__ void conv4_kernel(const float* __restrict__ in, const float* __restrict__ w,
                             const float* __restrict__ bias, float* __restrict__ out) {
    const int t = blockIdx.x * 256 + threadIdx.x;
    const int o = blockIdx.y;
    const int b = blockIdx.z;
    if (t >= L4_) return;
    float acc = bias[o];
    const float* inb = in + (size_t)b * 32 * L3_ + t;
    const float* wo = w + (size_t)o * 32 * 3;
    for (int c = 0; c < 32; ++c) {
        acc += inb[c * L3_] * wo[c * 3] + inb[c * L3_ + 1] * wo[c * 3 + 1] +
               inb[c * L3_ + 2] * wo[c * 3 + 2];
    }
    out[((size_t)b * 16 + o) * L4_ + t] = fmaxf(acc, 0.f);
}

// Fused DWT bands + conv5 + relu -> y5 [32,16,510]. grid(32), block 512
__global__ __launch_bounds__(512) void dwt_conv5_kernel(const float* __restrict__ y3,
                                                        const float* __restrict__ w5,
                                                        const float* __restrict__ b5,
                                                        float* __restrict__ y5) {
    const int b = blockIdx.x, l = threadIdx.x;  // l in [0,512)
    __shared__ float cm[L3_];
    __shared__ float bands[5][L3_];
    __shared__ float w5s[240];
    __shared__ float b5s[16];
    float s = 0.f;
    for (int ch = 0; ch < 32; ++ch) s += y3[((size_t)b * 32 + ch) * L3_ + l];
    cm[l] = s * (1.f / 32.f);
    if (l < 240) w5s[l] = w5[l];
    if (l < 16) b5s[l] = b5[l];
    __syncthreads();
    const float s1 = 0.70710678118654752440f;
    const float s2c = 0.5f;
    const float s3 = 0.35355339059327378f;
    const float s4 = 0.25f;
    const int b16 = l & ~15, b8 = l & ~7, b4v = l & ~3, b2v = l & ~1;
    float sa = 0.f, sb = 0.f;
#pragma unroll
    for (int i = 0; i < 8; ++i) { sa += cm[b16 + i]; sb += cm[b16 + 8 + i]; }
    bands[0][l] = (sa + sb) * s4;
    bands[1][l] = (sa - sb) * s4;
    float ta = 0.f, tb = 0.f;
#pragma unroll
    for (int i = 0; i < 4; ++i) { ta += cm[b8 + i]; tb += cm[b8 + 4 + i]; }
    bands[2][l] = (ta - tb) * s3;
    bands[3][l] = (cm[b4v] + cm[b4v + 1] - cm[b4v + 2] - cm[b4v + 3]) * s2c;
    bands[4][l] = (cm[b2v] - cm[b2v + 1]) * s1;
    __syncthreads();
    if (l < L4_) {
        float in3[5][3];
#pragma unroll
        for (int c = 0; c < 5; ++c) {
            in3[c][0] = bands[c][l]; in3[c][1] = bands[c][l + 1]; in3[c][2] = bands[c][l + 2];
        }
#pragma unroll
        for (int o = 0; o < 16; ++o) {
            float acc = b5s[o];
#pragma unroll
            for (int c = 0; c < 5; ++c) {
                const float* wp = &w5s[(o * 5 + c) * 3];
                acc += in3[c][0] * wp[0] + in3[c][1] * wp[1] + in3[c][2] * wp[2];
            }
            y5[((size_t)b * 16 + o) * L4_ + l] = fmaxf(acc, 0.f);
        }
    }
}

// Merged BN4-stats + BN5-stats + pooling + FC. grid(1), block 512.
__global__ __launch_bounds__(512) void tail_final_kernel(
        const float* __restrict__ y4, const float* __restrict__ y5,
        const float* __restrict__ g4, const float* __restrict__ be4,
        const float* __restrict__ g5, const float* __restrict__ be5,
        const float* __restrict__ fcw, const float* __restrict__ fcb,
        float* __restrict__ out) {
    const int p = threadIdx.x;           // 0..511
    const int b = p >> 4, ch = p & 15;
    const float2* p4 = (const float2*)(y4 + ((size_t)(b * 16 + ch)) * L4_);
    const float2* p5 = (const float2*)(y5 + ((size_t)(b * 16 + ch)) * L4_);
    float s4 = 0.f, q4 = 0.f, s5 = 0.f, q5 = 0.f;
    for (int i = 0; i < L4_ / 2; ++i) {
        float2 a = p4[i], bb2 = p5[i];
        s4 += a.x + a.y;  q4 += a.x * a.x + a.y * a.y;
        s5 += bb2.x + bb2.y; q5 += bb2.x * bb2.x + bb2.y * bb2.y;
    }
    __shared__ float S4[512], Q4[512], S5[512], Q5[512];
    __shared__ float M4[16], R4[16], M5[16], R5[16];
    __shared__ float pool[B_][16];
    S4[p] = s4; Q4[p] = q4; S5[p] = s5; Q5[p] = q5;
    __syncthreads();
    if (p < 16) {
        float ts = 0.f, tq = 0.f, us = 0.f, uq = 0.f;
        for (int bb = 0; bb < B_; ++bb) {
            ts += S4[bb * 16 + p]; tq += Q4[bb * 16 + p];
            us += S5[bb * 16 + p]; uq += Q5[bb * 16 + p];
        }
        const float n = (float)(B_ * L4_);
        float m = ts / n; M4[p] = m; R4[p] = rsqrtf(tq / n - m * m + 1e-5f);
        m = us / n;       M5[p] = m; R5[p] = rsqrtf(uq / n - m * m + 1e-5f);
    }
    __syncthreads();
    {
        const float mm4 = s4 / (float)L4_, mm5 = s5 / (float)L4_;
        const float v4 = (mm4 - M4[ch]) * R4[ch] * g4[ch] + be4[ch];
        const float v5 = (mm5 - M5[ch]) * R5[ch] * g5[ch] + be5[ch];
        pool[b][ch] = 0.5f * (v4 + v5);
    }
    __syncthreads();
    if (p < B_ * 10) {
        const int bb = p / 10, row = p - bb * 10;
        float a = fcb[row];
#pragma unroll
        for (int c = 0; c < 16; ++c) a += pool[bb][c] * fcw[row * 16 + c];
        out[bb * 10 + row] = a;
    }
}

// ---------------------------------------------------------------------------
extern "C" void kernel_launch(void* const* d_in, const int* in_sizes, int n_in,
                              void* d_out, int out_size, void* d_ws, size_t ws_size,
                              hipStream_t stream) {
    (void)in_sizes; (void)n_in; (void)out_size; (void)ws_size;
    const float* x   = (const float*)d_in[0];
    const float* wif = (const float*)d_in[1];
    const float* whf = (const float*)d_in[2];
    const float* bf  = (const float*)d_in[3];
    const float* wir = (const float*)d_in[4];
    const float* whr = (const float*)d_in[5];
    const float* br  = (const float*)d_in[6];
    const float* bw  = (const float*)d_in[7];
    const float* bb  = (const float*)d_in[8];
    const float* g1  = (const float*)d_in[9];  const float* be1 = (const float*)d_in[10];
    const float* g2  = (const float*)d_in[11]; const float* be2 = (const float*)d_in[12];
    const float* g3  = (const float*)d_in[13]; const float* be3 = (const float*)d_in[14];
    const float* g4  = (const float*)d_in[15]; const float* be4 = (const float*)d_in[16];
    const float* g5  = (const float*)d_in[17]; const float* be5 = (const float*)d_in[18];
    const float* w2  = (const float*)d_in[19]; const float* b2  = (const float*)d_in[20];
    const float* w3  = (const float*)d_in[21]; const float* b3  = (const float*)d_in[22];
    const float* w4  = (const float*)d_in[23]; const float* b4  = (const float*)d_in[24];
    const float* w5  = (const float*)d_in[25]; const float* b5  = (const float*)d_in[26];
    const float* fcw = (const float*)d_in[27]; const float* fcb = (const float*)d_in[28];
    float* out = (float*)d_out;
    float* ws  = (float*)d_ws;

    // Workspace layout (floats). xg region is reused by `wave` after the LSTM.
    float* xg_f  = ws;                       //  4,243,456
    float* xg_r  = ws + 4243456;             //  4,243,456
    float* wave  = ws;                       // 12,730,368 (reuses xg region)
    float* X     = ws + 12730368;            //  2,121,728
    float* y2    = ws + 14852096;            //  2,113,536
    float* y3    = ws + 16965632;            //    524,288
    float* y4    = ws + 17489920;            //    261,120
    float* y5    = ws + 17751040;            //    261,120
    float* stats = ws + 18012160;            //      1,536 (BN1 s/s2)
    float* m1 = ws + 18013696; float* r1 = m1 + 768;
    float* m2 = r1 + 768;      float* r2 = m2 + 128;
    float* m3 = r2 + 128;      float* r3 = m3 + 32;   // ends ~18,015,296 floats

    // 1) input projections (gate-interleaved layout, coalesced) + zero BN1 stats
    xg_kernel<<<dim3(65, 32), 256, 0, stream>>>(x, wif, bf, wir, br, xg_f, xg_r, stats);
    // 2) bidirectional LSTM recurrence -> X [32,128,518]  (one wave per chain)
    lstm_kernel<<<dim3(64), 64, 0, stream>>>(xg_f, xg_r, whf, whr, X);
    // 3) wave module -> wave [32,768,518], fused BN1 partial stats
    wave_kernel<<<dim3(3, CCH, B_), 256, 0, stream>>>(X, bw, bb, wave, stats);
    bn1_finalize_kernel<<<dim3(1), 768, 0, stream>>>(stats, m1, r1);
    bn_apply_row_kernel<<<dim3(B_ * WCH), 256, 0, stream>>>(wave, m1, r1, g1, be1, WCH, T_);
    // 5) conv2 + relu -> y2; BN2
    conv2_kernel<<<dim3(3, 16, B_), 256, 0, stream>>>(wave, w2, b2, y2);
    bn_stats_kernel<<<dim3(128), 256, 0, stream>>>(y2, B_, 128, L2_, m2, r2);
    bn_apply_row_kernel<<<dim3(B_ * 128), 256, 0, stream>>>(y2, m2, r2, g2, be2, 128, L2_);
    // 6) conv3 + relu -> y3; BN3
    conv3_kernel<<<dim3(2, 4, B_), 256, 0, stream>>>(y2, w3, b3, y3);
    bn_stats_kernel<<<dim3(32), 256, 0, stream>>>(y3, B_, 32, L3_, m3, r3);
    bn_apply_row_kernel<<<dim3(B_ * 32), 256, 0, stream>>>(y3, m3, r3, g3, be3, 32, L3_);
    // 7) conv4 + relu -> y4
    conv4_kernel<<<dim3(2, 16, B_), 256, 0, stream>>>(y3, w4, b4, y4);
    // 8) fused DWT + conv5 + relu -> y5
    dwt_conv5_kernel<<<dim3(B_), 512, 0, stream>>>(y3, w5, b5, y5);
    // 9) merged BN4/BN5 stats + pooling(+affine) + FC -> out [32,10]
    tail_final_kernel<<<dim3(1), 512, 0, stream>>>(y4, y5, g4, be4, g5, be5, fcw, fcb, out);
}

// Round 5
// 1078.748 us; speedup vs baseline: 1.2084x; 1.1132x over previous
//
#include <hip/hip_runtime.h>
#include <math.h>

// Problem constants
#define B_     32
#define F_     64
#define T_     518
#define HID    64
#define GATES  256   // 4*HID
#define CCH    128   // 2*HID lstm output channels
#define NWAVE  6
#define WCH    768   // NWAVE*CCH
#define L2_    516   // T-2   (conv2 out)
#define L3_    512   // L2-4  (conv3 out)
#define L4_    510   // L3-2  (conv4/conv5 out)

__device__ __forceinline__ float frcp(float x) { return __builtin_amdgcn_rcpf(x); }
__device__ __forceinline__ float fsigmoid(float x) { return frcp(1.f + __expf(-x)); }
__device__ __forceinline__ float ftanh(float x) { return 1.f - 2.f * frcp(1.f + __expf(2.f * x)); }

// ---------------------------------------------------------------------------
// K1: input projections, both dirs. Output layout xg[t][w][r][g2]:
//   flat offset = ((b*T + t)*256) + w*128 + r*2 + g2, where the gate row is
//   G = (2*w + g2)*64 + r. Thread tid stores at offset tid (fully coalesced):
//   w = tid>>7, g2 = tid&1, r = (tid>>1)&63.
// Block (0,0) also zeroes the BN1-stats accumulator.
// grid(65, 32), block 256
__global__ void xg_kernel(const float* __restrict__ x,
                          const float* __restrict__ wif, const float* __restrict__ bf,
                          const float* __restrict__ wir, const float* __restrict__ br,
                          float* __restrict__ xg_f, float* __restrict__ xg_r,
                          float* __restrict__ stats) {
    if (blockIdx.x == 0 && blockIdx.y == 0) {
        for (int i = threadIdx.x; i < 2 * WCH; i += 256) stats[i] = 0.f;
    }
    const int tid = threadIdx.x;
    const int wv  = tid >> 7;
    const int g2  = tid & 1;
    const int r   = (tid >> 1) & 63;
    const int g   = (2 * wv + g2) * 64 + r;       // gate row; store offset == tid
    const int b   = blockIdx.y;
    const int t0  = blockIdx.x * 8;
    float4 wa[16], wb[16];
    const float4* w0 = (const float4*)(wif + g * F_);
    const float4* w1 = (const float4*)(wir + g * F_);
#pragma unroll
    for (int i = 0; i < 16; ++i) { wa[i] = w0[i]; wb[i] = w1[i]; }
    const float bfv = bf[g], brv = br[g];
    for (int tt = 0; tt < 8; ++tt) {
        const int t = t0 + tt;
        if (t >= T_) break;
        const float* xp = x + (size_t)b * F_ * T_ + t;
        float a0 = bfv, a1 = brv;
#pragma unroll
        for (int i = 0; i < 16; ++i) {
            float x0 = xp[(i * 4 + 0) * T_];
            float x1 = xp[(i * 4 + 1) * T_];
            float x2 = xp[(i * 4 + 2) * T_];
            float x3 = xp[(i * 4 + 3) * T_];
            a0 += wa[i].x * x0 + wa[i].y * x1 + wa[i].z * x2 + wa[i].w * x3;
            a1 += wb[i].x * x0 + wb[i].y * x1 + wb[i].z * x2 + wb[i].w * x3;
        }
        const size_t o = ((size_t)b * T_ + t) * GATES + tid;   // coalesced
        xg_f[o] = a0;
        xg_r[o] = a1;
    }
}

// ---------------------------------------------------------------------------
// K2: LSTM recurrence — TWO waves per (b,dir), gates split across waves.
// Wave w lane r owns gate rows 2w and 2w+1 (128 weight floats = 128 VGPRs,
// comfortably register-resident — R2/R3 showed 256 floats/lane spills).
// Gate pre-activations exchanged via double-buffered LDS + raw s_barrier
// (lgkmcnt-only fence: vmcnt NOT drained, xg prefetch/X stores stay in
// flight). Both waves redundantly compute c/h; each wave keeps a private
// hs copy so h needs no cross-wave sync. grid(64), block 128.
__global__ __launch_bounds__(128, 1) void lstm_kernel(
        const float* __restrict__ xgi_f, const float* __restrict__ xgi_r,
        const float* __restrict__ whf, const float* __restrict__ whr,
        float* __restrict__ X) {
    const int dir = blockIdx.x & 1;
    const int b   = blockIdx.x >> 1;
    const float* xg  = (dir ? xgi_r : xgi_f) + (size_t)b * T_ * GATES;
    const float* whh = dir ? whr : whf;
    const int tid = threadIdx.x;
    const int r   = tid & 63;
    const int w   = tid >> 6;            // wave 0: gates i,f ; wave 1: gates g,o

    float4 wA[16], wB[16];
    {
        const float4* pA = (const float4*)(whh + (size_t)((2 * w) * HID + r) * HID);
        const float4* pB = (const float4*)(whh + (size_t)((2 * w + 1) * HID + r) * HID);
#pragma unroll
        for (int i = 0; i < 16; ++i) { wA[i] = pA[i]; wB[i] = pB[i]; }
    }

    __shared__ __align__(16) float hs[2][HID];        // per-wave private h
    __shared__ __align__(16) float gbuf[2][HID][4];   // double-buffered gates
    hs[w][r] = 0.f;
    float c = 0.f;
    float* Xrow = X + ((size_t)(b * CCH + dir * HID + r)) * T_;

    int t = dir ? (T_ - 1) : 0;
    const int step = dir ? -1 : 1;
    const float2* xg2 = (const float2*)xg;   // index (t*2 + w)*64 + r
    float2 q0 = xg2[((size_t)t * 2 + w) * 64 + r];
    float2 q1 = xg2[((size_t)(t + step) * 2 + w) * 64 + r];

    for (int s = 0; s < T_; ++s) {
        float4 a0 = {q0.x, 0.f, 0.f, 0.f};
        float4 a1 = {q0.y, 0.f, 0.f, 0.f};
        const float4* h4p = (const float4*)hs[w];
#pragma unroll
        for (int i = 0; i < 16; ++i) {
            const float4 h4 = h4p[i];
            a0.x = fmaf(wA[i].x, h4.x, a0.x); a0.y = fmaf(wA[i].y, h4.y, a0.y);
            a0.z = fmaf(wA[i].z, h4.z, a0.z); a0.w = fmaf(wA[i].w, h4.w, a0.w);
            a1.x = fmaf(wB[i].x, h4.x, a1.x); a1.y = fmaf(wB[i].y, h4.y, a1.y);
            a1.z = fmaf(wB[i].z, h4.z, a1.z); a1.w = fmaf(wB[i].w, h4.w, a1.w);
        }
        const float gA = (a0.x + a0.y) + (a0.z + a0.w);
        const float gB = (a1.x + a1.y) + (a1.z + a1.w);
        const int buf = s & 1;
        *(float2*)&gbuf[buf][r][2 * w] = make_float2(gA, gB);

        // depth-2 prefetch (clamped; harmless dup loads at the tail)
        int tp = t + 2 * step;
        tp = tp < 0 ? 0 : (tp >= T_ ? T_ - 1 : tp);
        const float2 qn = xg2[((size_t)tp * 2 + w) * 64 + r];

        // LDS-only fence + raw barrier: gbuf writes visible, vmcnt untouched.
        // The memory clobber also pins the pre-loop weight loads (cannot be
        // sunk across a clobber) — keeps wA/wB register-resident.
        asm volatile("s_waitcnt lgkmcnt(0)" ::: "memory");
        __builtin_amdgcn_s_barrier();

        const float4 g4 = *(const float4*)gbuf[buf][r];   // i,f,g,o
        const float si = fsigmoid(g4.x);
        const float sf = fsigmoid(g4.y);
        const float so = fsigmoid(g4.w);
        c = sf * c + si * ftanh(g4.z);
        const float h = so * ftanh(c);

        hs[w][r] = h;              // own copy; in-order DS pipe orders vs reads
        if (w == 0) Xrow[t] = h;   // wave-uniform branch
        q0 = q1; q1 = qn;
        t += step;
    }
}

// ---------------------------------------------------------------------------
// K3: wave module + fused BN1 partial stats (atomics into `stats`).
// grid(ceil(T/256)=3, 128, 32), block 256
__global__ void wave_kernel(const float* __restrict__ X,
                            const float* __restrict__ bw, const float* __restrict__ bb,
                            float* __restrict__ wave, float* __restrict__ stats) {
    const int b = blockIdx.z, c = blockIdx.y;
    const int t0 = blockIdx.x * 256;
    const int tid = threadIdx.x;
    __shared__ float xs[256 + 14];
    __shared__ float bws[NWAVE][16];
    __shared__ float bbs[NWAVE];
    __shared__ float red[4][12];
    const float* xrow = X + ((size_t)(b * CCH + c)) * T_;
    for (int i = tid; i < 270; i += 256) {
        int tt = t0 - 7 + i;
        xs[i] = (tt >= 0 && tt < T_) ? xrow[tt] : 0.f;
    }
    if (tid < NWAVE * 15) bws[tid / 15][tid % 15] = bw[tid];
    if (tid < NWAVE) bbs[tid] = bb[tid];
    __syncthreads();
    const int t = t0 + tid;
    float ls[NWAVE], lq[NWAVE];
#pragma unroll
    for (int ii = 0; ii < NWAVE; ++ii) { ls[ii] = 0.f; lq[ii] = 0.f; }
    if (t < T_) {
        float win[15];
#pragma unroll
        for (int k = 0; k < 15; ++k) win[k] = xs[tid + k];
        float e[8];
        e[0] = win[7];
#pragma unroll
        for (int m = 1; m < 8; ++m) e[m] = win[7 - m] + win[7 + m];
        const float c0 = 6.28318530717958647692f / 15.f;  // 2*pi/WIDE
#pragma unroll
        for (int ii = 0; ii < NWAVE; ++ii) {
            float sc = bbs[ii];
#pragma unroll
            for (int k = 0; k < 15; ++k) sc += win[k] * bws[ii][k];
            sc = fmaxf(sc, 0.f);
            const float phi = c0 * (float)(ii + 1) * sc;
            float o = e[0];
#pragma unroll
            for (int m = 1; m < 8; ++m) o += e[m] * __cosf(phi * (float)m);
            const float q = (truncf(sc * 15.f) + 1.f) * (2.f / 17.f);
            const float val = o * rsqrtf(q);
            wave[((size_t)(b * WCH + ii * CCH + c)) * T_ + t] = val;
            ls[ii] = val;
            lq[ii] = val * val;
        }
    }
    // block reduction of the 12 partials, then atomics (96 blocks/channel)
#pragma unroll
    for (int off = 32; off > 0; off >>= 1) {
#pragma unroll
        for (int ii = 0; ii < NWAVE; ++ii) {
            ls[ii] += __shfl_down(ls[ii], off);
            lq[ii] += __shfl_down(lq[ii], off);
        }
    }
    if ((tid & 63) == 0) {
        const int w = tid >> 6;
#pragma unroll
        for (int ii = 0; ii < NWAVE; ++ii) { red[w][ii] = ls[ii]; red[w][6 + ii] = lq[ii]; }
    }
    __syncthreads();
    if (tid < 12) {
        const float a = red[0][tid] + red[1][tid] + red[2][tid] + red[3][tid];
        const int ii = tid % 6;
        const int ch = ii * CCH + c;
        atomicAdd(&stats[(tid >= 6 ? WCH : 0) + ch], a);
    }
}

// Finalize BN1 stats: 1 block, 768 threads
__global__ void bn1_finalize_kernel(const float* __restrict__ stats,
                                    float* __restrict__ mean, float* __restrict__ rstd) {
    const int c = threadIdx.x;
    const float n = (float)(B_ * T_);
    const float m = stats[c] / n;
    const float v = stats[WCH + c] / n - m * m;
    mean[c] = m;
    rstd[c] = rsqrtf(v + 1e-5f);
}

// ---------------------------------------------------------------------------
// Generic training-mode BN statistics: one block per channel
__global__ void bn_stats_kernel(const float* __restrict__ x, int Bn, int C, int L,
                                float* __restrict__ mean, float* __restrict__ rstd) {
    const int c = blockIdx.x;
    const int tid = threadIdx.x;
    float s = 0.f, s2 = 0.f;
    for (int b = 0; b < Bn; ++b) {
        const float* row = x + ((size_t)b * C + c) * L;
        for (int l = tid; l < L; l += 256) { float v = row[l]; s += v; s2 += v * v; }
    }
#pragma unroll
    for (int off = 32; off > 0; off >>= 1) { s += __shfl_down(s, off); s2 += __shfl_down(s2, off); }
    __shared__ float ss[4], ss2[4];
    if ((tid & 63) == 0) { ss[tid >> 6] = s; ss2[tid >> 6] = s2; }
    __syncthreads();
    if (tid == 0) {
        float S = ss[0] + ss[1] + ss[2] + ss[3];
        float S2 = ss2[0] + ss2[1] + ss2[2] + ss2[3];
        float n = (float)(Bn * L);
        float m = S / n;
        float v = S2 / n - m * m;
        mean[c] = m;
        rstd[c] = rsqrtf(v + 1e-5f);
    }
}

// In-place BN affine apply, one block per (b,c) row (no per-element int div)
__global__ void bn_apply_row_kernel(float* __restrict__ x, const float* __restrict__ mean,
                                    const float* __restrict__ rstd, const float* __restrict__ g,
                                    const float* __restrict__ be, int C, int L) {
    const int row = blockIdx.x;
    const int c = row % C;
    const float sc = rstd[c] * g[c];
    const float sh = be[c] - mean[c] * sc;
    float* p = x + (size_t)row * L;
    for (int l = threadIdx.x; l < L; l += 256) p[l] = p[l] * sc + sh;
}

// ---------------------------------------------------------------------------
// conv2: [32,768,518] -> relu -> [32,128,516], k=3. grid(3,16,32), block 256
__global__ void conv2_kernel(const float* __restrict__ in, const float* __restrict__ w,
                             const float* __restrict__ bias, float* __restrict__ out) {
    const int t = blockIdx.x * 256 + threadIdx.x;
    const int o0 = blockIdx.y * 8;
    const int b = blockIdx.z;
    if (t >= L2_) return;
    float acc[8];
#pragma unroll
    for (int j = 0; j < 8; ++j) acc[j] = bias[o0 + j];
    const float* inb = in + (size_t)b * WCH * T_ + t;
    const float* wb = w + (size_t)o0 * WCH * 3;
    for (int c = 0; c < WCH; ++c) {
        float x0 = inb[c * T_], x1 = inb[c * T_ + 1], x2 = inb[c * T_ + 2];
        const float* wc = wb + c * 3;
#pragma unroll
        for (int j = 0; j < 8; ++j) {
            const float* wj = wc + (size_t)j * WCH * 3;
            acc[j] += x0 * wj[0] + x1 * wj[1] + x2 * wj[2];
        }
    }
    const size_t ob = ((size_t)b * 128 + o0) * L2_ + t;
#pragma unroll
    for (int j = 0; j < 8; ++j) out[ob + (size_t)j * L2_] = fmaxf(acc[j], 0.f);
}

// conv3: [32,128,516] -> relu -> [32,32,512], k=5. grid(2,4,32), block 256
__global__ void conv3_kernel(const float* __restrict__ in, const float* __restrict__ w,
                             const float* __restrict__ bias, float* __restrict__ out) {
    const int t = blockIdx.x * 256 + threadIdx.x;
    const int o0 = blockIdx.y * 8;
    const int b = blockIdx.z;
    if (t >= L3_) return;
    float acc[8];
#pragma unroll
    for (int j = 0; j < 8; ++j) acc[j] = bias[o0 + j];
    const float* inb = in + (size_t)b * 128 * L2_ + t;
    const float* wb = w + (size_t)o0 * 128 * 5;
    for (int c = 0; c < 128; ++c) {
        float x0 = inb[c * L2_], x1 = inb[c * L2_ + 1], x2 = inb[c * L2_ + 2];
        float x3 = inb[c * L2_ + 3], x4 = inb[c * L2_ + 4];
        const float* wc = wb + c * 5;
#pragma unroll
        for (int j = 0; j < 8; ++j) {
            const float* wj = wc + (size_t)j * 128 * 5;
            acc[j] += x0 * wj[0] + x1 * wj[1] + x2 * wj[2] + x3 * wj[3] + x4 * wj[4];
        }
    }
    const size_t ob = ((size_t)b * 32 + o0) * L3_ + t;
#pragma unroll
    for (int j = 0; j < 8; ++j) out[ob + (size_t)j * L3_] = fmaxf(acc[j], 0.f);
}

// conv4: [32,32,512] -> relu -> [32,16,510], k=3. grid(2,16,32), block 256
__global__ void conv4_kernel(const float* __restrict__ in, const float* __restrict__ w,
                             const float* __restrict__ bias, float* __restrict__ out) {
    const int t = blockIdx.x * 256 + threadIdx.x;
    const int o = blockIdx.y;
    const int b = blockIdx.z;
    if (t >= L4_) return;
    float acc = bias[o];
    const float* inb = in + (size_t)b * 32 * L3_ + t;
    const float* wo = w + (size_t)o * 32 * 3;
    for (int c = 0; c < 32; ++c) {
        acc += inb[c * L3_] * wo[c * 3] + inb[c * L3_ + 1] * wo[c * 3 + 1] +
               inb[c * L3_ + 2] * wo[c * 3 + 2];
    }
    out[((size_t)b * 16 + o) * L4_ + t] = fmaxf(acc, 0.f);
}

// Fused DWT bands + conv5 + relu -> y5 [32,16,510]. grid(32), block 512
__global__ __launch_bounds__(512) void dwt_conv5_kernel(const float* __restrict__ y3,
                                                        const float* __restrict__ w5,
                                                        const float* __restrict__ b5,
                                                        float* __restrict__ y5) {
    const int b = blockIdx.x, l = threadIdx.x;  // l in [0,512)
    __shared__ float cm[L3_];
    __shared__ float bands[5][L3_];
    __shared__ float w5s[240];
    __shared__ float b5s[16];
    float s = 0.f;
    for (int ch = 0; ch < 32; ++ch) s += y3[((size_t)b * 32 + ch) * L3_ + l];
    cm[l] = s * (1.f / 32.f);
    if (l < 240) w5s[l] = w5[l];
    if (l < 16) b5s[l] = b5[l];
    __syncthreads();
    const float s1 = 0.70710678118654752440f;
    const float s2c = 0.5f;
    const float s3 = 0.35355339059327378f;
    const float s4 = 0.25f;
    const int b16 = l & ~15, b8 = l & ~7, b4v = l & ~3, b2v = l & ~1;
    float sa = 0.f, sb = 0.f;
#pragma unroll
    for (int i = 0; i < 8; ++i) { sa += cm[b16 + i]; sb += cm[b16 + 8 + i]; }
    bands[0][l] = (sa + sb) * s4;
    bands[1][l] = (sa - sb) * s4;
    float ta = 0.f, tb = 0.f;
#pragma unroll
    for (int i = 0; i < 4; ++i) { ta += cm[b8 + i]; tb += cm[b8 + 4 + i]; }
    bands[2][l] = (ta - tb) * s3;
    bands[3][l] = (cm[b4v] + cm[b4v + 1] - cm[b4v + 2] - cm[b4v + 3]) * s2c;
    bands[4][l] = (cm[b2v] - cm[b2v + 1]) * s1;
    __syncthreads();
    if (l < L4_) {
        float in3[5][3];
#pragma unroll
        for (int c = 0; c < 5; ++c) {
            in3[c][0] = bands[c][l]; in3[c][1] = bands[c][l + 1]; in3[c][2] = bands[c][l + 2];
        }
#pragma unroll
        for (int o = 0; o < 16; ++o) {
            float acc = b5s[o];
#pragma unroll
            for (int c = 0; c < 5; ++c) {
                const float* wp = &w5s[(o * 5 + c) * 3];
                acc += in3[c][0] * wp[0] + in3[c][1] * wp[1] + in3[c][2] * wp[2];
            }
            y5[((size_t)b * 16 + o) * L4_ + l] = fmaxf(acc, 0.f);
        }
    }
}

// Merged BN4-stats + BN5-stats + pooling + FC. grid(1), block 512.
__global__ __launch_bounds__(512) void tail_final_kernel(
        const float* __restrict__ y4, const float* __restrict__ y5,
        const float* __restrict__ g4, const float* __restrict__ be4,
        const float* __restrict__ g5, const float* __restrict__ be5,
        const float* __restrict__ fcw, const float* __restrict__ fcb,
        float* __restrict__ out) {
    const int p = threadIdx.x;           // 0..511
    const int b = p >> 4, ch = p & 15;
    const float2* p4 = (const float2*)(y4 + ((size_t)(b * 16 + ch)) * L4_);
    const float2* p5 = (const float2*)(y5 + ((size_t)(b * 16 + ch)) * L4_);
    float s4 = 0.f, q4 = 0.f, s5 = 0.f, q5 = 0.f;
    for (int i = 0; i < L4_ / 2; ++i) {
        float2 a = p4[i], bb2 = p5[i];
        s4 += a.x + a.y;  q4 += a.x * a.x + a.y * a.y;
        s5 += bb2.x + bb2.y; q5 += bb2.x * bb2.x + bb2.y * bb2.y;
    }
    __shared__ float S4[512], Q4[512], S5[512], Q5[512];
    __shared__ float M4[16], R4[16], M5[16], R5[16];
    __shared__ float pool[B_][16];
    S4[p] = s4; Q4[p] = q4; S5[p] = s5; Q5[p] = q5;
    __syncthreads();
    if (p < 16) {
        float ts = 0.f, tq = 0.f, us = 0.f, uq = 0.f;
        for (int bb = 0; bb < B_; ++bb) {
            ts += S4[bb * 16 + p]; tq += Q4[bb * 16 + p];
            us += S5[bb * 16 + p]; uq += Q5[bb * 16 + p];
        }
        const float n = (float)(B_ * L4_);
        float m = ts / n; M4[p] = m; R4[p] = rsqrtf(tq / n - m * m + 1e-5f);
        m = us / n;       M5[p] = m; R5[p] = rsqrtf(uq / n - m * m + 1e-5f);
    }
    __syncthreads();
    {
        const float mm4 = s4 / (float)L4_, mm5 = s5 / (float)L4_;
        const float v4 = (mm4 - M4[ch]) * R4[ch] * g4[ch] + be4[ch];
        const float v5 = (mm5 - M5[ch]) * R5[ch] * g5[ch] + be5[ch];
        pool[b][ch] = 0.5f * (v4 + v5);
    }
    __syncthreads();
    if (p < B_ * 10) {
        const int bb = p / 10, row = p - bb * 10;
        float a = fcb[row];
#pragma unroll
        for (int c = 0; c < 16; ++c) a += pool[bb][c] * fcw[row * 16 + c];
        out[bb * 10 + row] = a;
    }
}

// ---------------------------------------------------------------------------
extern "C" void kernel_launch(void* const* d_in, const int* in_sizes, int n_in,
                              void* d_out, int out_size, void* d_ws, size_t ws_size,
                              hipStream_t stream) {
    (void)in_sizes; (void)n_in; (void)out_size; (void)ws_size;
    const float* x   = (const float*)d_in[0];
    const float* wif = (const float*)d_in[1];
    const float* whf = (const float*)d_in[2];
    const float* bf  = (const float*)d_in[3];
    const float* wir = (const float*)d_in[4];
    const float* whr = (const float*)d_in[5];
    const float* br  = (const float*)d_in[6];
    const float* bw  = (const float*)d_in[7];
    const float* bb  = (const float*)d_in[8];
    const float* g1  = (const float*)d_in[9];  const float* be1 = (const float*)d_in[10];
    const float* g2  = (const float*)d_in[11]; const float* be2 = (const float*)d_in[12];
    const float* g3  = (const float*)d_in[13]; const float* be3 = (const float*)d_in[14];
    const float* g4  = (const float*)d_in[15]; const float* be4 = (const float*)d_in[16];
    const float* g5  = (const float*)d_in[17]; const float* be5 = (const float*)d_in[18];
    const float* w2  = (const float*)d_in[19]; const float* b2  = (const float*)d_in[20];
    const float* w3  = (const float*)d_in[21]; const float* b3  = (const float*)d_in[22];
    const float* w4  = (const float*)d_in[23]; const float* b4  = (const float*)d_in[24];
    const float* w5  = (const float*)d_in[25]; const float* b5  = (const float*)d_in[26];
    const float* fcw = (const float*)d_in[27]; const float* fcb = (const float*)d_in[28];
    float* out = (float*)d_out;
    float* ws  = (float*)d_ws;

    // Workspace layout (floats). xg region is reused by `wave` after the LSTM.
    float* xg_f  = ws;                       //  4,243,456
    float* xg_r  = ws + 4243456;             //  4,243,456
    float* wave  = ws;                       // 12,730,368 (reuses xg region)
    float* X     = ws + 12730368;            //  2,121,728
    float* y2    = ws + 14852096;            //  2,113,536
    float* y3    = ws + 16965632;            //    524,288
    float* y4    = ws + 17489920;            //    261,120
    float* y5    = ws + 17751040;            //    261,120
    float* stats = ws + 18012160;            //      1,536 (BN1 s/s2)
    float* m1 = ws + 18013696; float* r1 = m1 + 768;
    float* m2 = r1 + 768;      float* r2 = m2 + 128;
    float* m3 = r2 + 128;      float* r3 = m3 + 32;   // ends ~18,015,296 floats

    // 1) input projections (wave-split gate-pair layout, coalesced) + zero BN1 stats
    xg_kernel<<<dim3(65, 32), 256, 0, stream>>>(x, wif, bf, wir, br, xg_f, xg_r, stats);
    // 2) bidirectional LSTM recurrence -> X [32,128,518]  (two waves per chain)
    lstm_kernel<<<dim3(64), 128, 0, stream>>>(xg_f, xg_r, whf, whr, X);
    // 3) wave module -> wave [32,768,518], fused BN1 partial stats
    wave_kernel<<<dim3(3, CCH, B_), 256, 0, stream>>>(X, bw, bb, wave, stats);
    bn1_finalize_kernel<<<dim3(1), 768, 0, stream>>>(stats, m1, r1);
    bn_apply_row_kernel<<<dim3(B_ * WCH), 256, 0, stream>>>(wave, m1, r1, g1, be1, WCH, T_);
    // 5) conv2 + relu -> y2; BN2
    conv2_kernel<<<dim3(3, 16, B_), 256, 0, stream>>>(wave, w2, b2, y2);
    bn_stats_kernel<<<dim3(128), 256, 0, stream>>>(y2, B_, 128, L2_, m2, r2);
    bn_apply_row_kernel<<<dim3(B_ * 128), 256, 0, stream>>>(y2, m2, r2, g2, be2, 128, L2_);
    // 6) conv3 + relu -> y3; BN3
    conv3_kernel<<<dim3(2, 4, B_), 256, 0, stream>>>(y2, w3, b3, y3);
    bn_stats_kernel<<<dim3(32), 256, 0, stream>>>(y3, B_, 32, L3_, m3, r3);
    bn_apply_row_kernel<<<dim3(B_ * 32), 256, 0, stream>>>(y3, m3, r3, g3, be3, 32, L3_);
    // 7) conv4 + relu -> y4
    conv4_kernel<<<dim3(2, 16, B_), 256, 0, stream>>>(y3, w4, b4, y4);
    // 8) fused DWT + conv5 + relu -> y5
    dwt_conv5_kernel<<<dim3(B_), 512, 0, stream>>>(y3, w5, b5, y5);
    // 9) merged BN4/BN5 stats + pooling(+affine) + FC -> out [32,10]
    tail_final_kernel<<<dim3(1), 512, 0, stream>>>(y4, y5, g4, be4, g5, be5, fcw, fcb, out);
}

// Round 6
// 1023.168 us; speedup vs baseline: 1.2740x; 1.0543x over previous
//
#include <hip/hip_runtime.h>
#include <math.h>

// Problem constants
#define B_     32
#define F_     64
#define T_     518
#define HID    64
#define GATES  256   // 4*HID
#define CCH    128   // 2*HID lstm output channels
#define NWAVE  6
#define WCH    768   // NWAVE*CCH
#define L2_    516   // T-2   (conv2 out)
#define L3_    512   // L2-4  (conv3 out)
#define L4_    510   // L3-2  (conv4/conv5 out)

__device__ __forceinline__ float frcp(float x) { return __builtin_amdgcn_rcpf(x); }
__device__ __forceinline__ float fsigmoid(float x) { return frcp(1.f + __expf(-x)); }
__device__ __forceinline__ float ftanh(float x) { return 1.f - 2.f * frcp(1.f + __expf(2.f * x)); }

// ---------------------------------------------------------------------------
// K1: input projections, both dirs. Output layout xg[t][w][r][g2] (coalesced).
__global__ void xg_kernel(const float* __restrict__ x,
                          const float* __restrict__ wif, const float* __restrict__ bf,
                          const float* __restrict__ wir, const float* __restrict__ br,
                          float* __restrict__ xg_f, float* __restrict__ xg_r,
                          float* __restrict__ stats) {
    if (blockIdx.x == 0 && blockIdx.y == 0) {
        for (int i = threadIdx.x; i < 2 * WCH; i += 256) stats[i] = 0.f;
    }
    const int tid = threadIdx.x;
    const int wv  = tid >> 7;
    const int g2  = tid & 1;
    const int r   = (tid >> 1) & 63;
    const int g   = (2 * wv + g2) * 64 + r;       // gate row; store offset == tid
    const int b   = blockIdx.y;
    const int t0  = blockIdx.x * 8;
    float4 wa[16], wb[16];
    const float4* w0 = (const float4*)(wif + g * F_);
    const float4* w1 = (const float4*)(wir + g * F_);
#pragma unroll
    for (int i = 0; i < 16; ++i) { wa[i] = w0[i]; wb[i] = w1[i]; }
    const float bfv = bf[g], brv = br[g];
    for (int tt = 0; tt < 8; ++tt) {
        const int t = t0 + tt;
        if (t >= T_) break;
        const float* xp = x + (size_t)b * F_ * T_ + t;
        float a0 = bfv, a1 = brv;
#pragma unroll
        for (int i = 0; i < 16; ++i) {
            float x0 = xp[(i * 4 + 0) * T_];
            float x1 = xp[(i * 4 + 1) * T_];
            float x2 = xp[(i * 4 + 2) * T_];
            float x3 = xp[(i * 4 + 3) * T_];
            a0 += wa[i].x * x0 + wa[i].y * x1 + wa[i].z * x2 + wa[i].w * x3;
            a1 += wb[i].x * x0 + wb[i].y * x1 + wb[i].z * x2 + wb[i].w * x3;
        }
        const size_t o = ((size_t)b * T_ + t) * GATES + tid;   // coalesced
        xg_f[o] = a0;
        xg_r[o] = a1;
    }
}

// ---------------------------------------------------------------------------
// K2: LSTM recurrence — TWO waves per (b,dir), gates split across waves.
// (R4 structure: 128 weight floats/lane register-resident, lgkmcnt-only
// barrier, depth-2 xg prefetch.) grid(64), block 128.
__global__ __launch_bounds__(128, 1) void lstm_kernel(
        const float* __restrict__ xgi_f, const float* __restrict__ xgi_r,
        const float* __restrict__ whf, const float* __restrict__ whr,
        float* __restrict__ X) {
    const int dir = blockIdx.x & 1;
    const int b   = blockIdx.x >> 1;
    const float* xg  = (dir ? xgi_r : xgi_f) + (size_t)b * T_ * GATES;
    const float* whh = dir ? whr : whf;
    const int tid = threadIdx.x;
    const int r   = tid & 63;
    const int w   = tid >> 6;            // wave 0: gates i,f ; wave 1: gates g,o

    float4 wA[16], wB[16];
    {
        const float4* pA = (const float4*)(whh + (size_t)((2 * w) * HID + r) * HID);
        const float4* pB = (const float4*)(whh + (size_t)((2 * w + 1) * HID + r) * HID);
#pragma unroll
        for (int i = 0; i < 16; ++i) { wA[i] = pA[i]; wB[i] = pB[i]; }
    }

    __shared__ __align__(16) float hs[2][HID];        // per-wave private h
    __shared__ __align__(16) float gbuf[2][HID][4];   // double-buffered gates
    hs[w][r] = 0.f;
    float c = 0.f;
    float* Xrow = X + ((size_t)(b * CCH + dir * HID + r)) * T_;

    int t = dir ? (T_ - 1) : 0;
    const int step = dir ? -1 : 1;
    const float2* xg2 = (const float2*)xg;   // index (t*2 + w)*64 + r
    float2 q0 = xg2[((size_t)t * 2 + w) * 64 + r];
    float2 q1 = xg2[((size_t)(t + step) * 2 + w) * 64 + r];

    for (int s = 0; s < T_; ++s) {
        float4 a0 = {q0.x, 0.f, 0.f, 0.f};
        float4 a1 = {q0.y, 0.f, 0.f, 0.f};
        const float4* h4p = (const float4*)hs[w];
#pragma unroll
        for (int i = 0; i < 16; ++i) {
            const float4 h4 = h4p[i];
            a0.x = fmaf(wA[i].x, h4.x, a0.x); a0.y = fmaf(wA[i].y, h4.y, a0.y);
            a0.z = fmaf(wA[i].z, h4.z, a0.z); a0.w = fmaf(wA[i].w, h4.w, a0.w);
            a1.x = fmaf(wB[i].x, h4.x, a1.x); a1.y = fmaf(wB[i].y, h4.y, a1.y);
            a1.z = fmaf(wB[i].z, h4.z, a1.z); a1.w = fmaf(wB[i].w, h4.w, a1.w);
        }
        const float gA = (a0.x + a0.y) + (a0.z + a0.w);
        const float gB = (a1.x + a1.y) + (a1.z + a1.w);
        const int buf = s & 1;
        *(float2*)&gbuf[buf][r][2 * w] = make_float2(gA, gB);

        int tp = t + 2 * step;
        tp = tp < 0 ? 0 : (tp >= T_ ? T_ - 1 : tp);
        const float2 qn = xg2[((size_t)tp * 2 + w) * 64 + r];

        asm volatile("s_waitcnt lgkmcnt(0)" ::: "memory");
        __builtin_amdgcn_s_barrier();

        const float4 g4 = *(const float4*)gbuf[buf][r];   // i,f,g,o
        const float si = fsigmoid(g4.x);
        const float sf = fsigmoid(g4.y);
        const float so = fsigmoid(g4.w);
        c = sf * c + si * ftanh(g4.z);
        const float h = so * ftanh(c);

        hs[w][r] = h;
        if (w == 0) Xrow[t] = h;
        q0 = q1; q1 = qn;
        t += step;
    }
}

// ---------------------------------------------------------------------------
// K3: wave module + fused BN1 partial stats. grid(3, 128, 32), block 256
__global__ void wave_kernel(const float* __restrict__ X,
                            const float* __restrict__ bw, const float* __restrict__ bb,
                            float* __restrict__ wave, float* __restrict__ stats) {
    const int b = blockIdx.z, c = blockIdx.y;
    const int t0 = blockIdx.x * 256;
    const int tid = threadIdx.x;
    __shared__ float xs[256 + 14];
    __shared__ float bws[NWAVE][16];
    __shared__ float bbs[NWAVE];
    __shared__ float red[4][12];
    const float* xrow = X + ((size_t)(b * CCH + c)) * T_;
    for (int i = tid; i < 270; i += 256) {
        int tt = t0 - 7 + i;
        xs[i] = (tt >= 0 && tt < T_) ? xrow[tt] : 0.f;
    }
    if (tid < NWAVE * 15) bws[tid / 15][tid % 15] = bw[tid];
    if (tid < NWAVE) bbs[tid] = bb[tid];
    __syncthreads();
    const int t = t0 + tid;
    float ls[NWAVE], lq[NWAVE];
#pragma unroll
    for (int ii = 0; ii < NWAVE; ++ii) { ls[ii] = 0.f; lq[ii] = 0.f; }
    if (t < T_) {
        float win[15];
#pragma unroll
        for (int k = 0; k < 15; ++k) win[k] = xs[tid + k];
        float e[8];
        e[0] = win[7];
#pragma unroll
        for (int m = 1; m < 8; ++m) e[m] = win[7 - m] + win[7 + m];
        const float c0 = 6.28318530717958647692f / 15.f;  // 2*pi/WIDE
#pragma unroll
        for (int ii = 0; ii < NWAVE; ++ii) {
            float sc = bbs[ii];
#pragma unroll
            for (int k = 0; k < 15; ++k) sc += win[k] * bws[ii][k];
            sc = fmaxf(sc, 0.f);
            const float phi = c0 * (float)(ii + 1) * sc;
            float o = e[0];
#pragma unroll
            for (int m = 1; m < 8; ++m) o += e[m] * __cosf(phi * (float)m);
            const float q = (truncf(sc * 15.f) + 1.f) * (2.f / 17.f);
            const float val = o * rsqrtf(q);
            wave[((size_t)(b * WCH + ii * CCH + c)) * T_ + t] = val;
            ls[ii] = val;
            lq[ii] = val * val;
        }
    }
#pragma unroll
    for (int off = 32; off > 0; off >>= 1) {
#pragma unroll
        for (int ii = 0; ii < NWAVE; ++ii) {
            ls[ii] += __shfl_down(ls[ii], off);
            lq[ii] += __shfl_down(lq[ii], off);
        }
    }
    if ((tid & 63) == 0) {
        const int w = tid >> 6;
#pragma unroll
        for (int ii = 0; ii < NWAVE; ++ii) { red[w][ii] = ls[ii]; red[w][6 + ii] = lq[ii]; }
    }
    __syncthreads();
    if (tid < 12) {
        const float a = red[0][tid] + red[1][tid] + red[2][tid] + red[3][tid];
        const int ii = tid % 6;
        const int ch = ii * CCH + c;
        atomicAdd(&stats[(tid >= 6 ? WCH : 0) + ch], a);
    }
}

// Finalize BN1 stats: 1 block, 768 threads
__global__ void bn1_finalize_kernel(const float* __restrict__ stats,
                                    float* __restrict__ mean, float* __restrict__ rstd) {
    const int c = threadIdx.x;
    const float n = (float)(B_ * T_);
    const float m = stats[c] / n;
    const float v = stats[WCH + c] / n - m * m;
    mean[c] = m;
    rstd[c] = rsqrtf(v + 1e-5f);
}

// ---------------------------------------------------------------------------
// Generic training-mode BN statistics: one block per channel
__global__ void bn_stats_kernel(const float* __restrict__ x, int Bn, int C, int L,
                                float* __restrict__ mean, float* __restrict__ rstd) {
    const int c = blockIdx.x;
    const int tid = threadIdx.x;
    float s = 0.f, s2 = 0.f;
    for (int b = 0; b < Bn; ++b) {
        const float* row = x + ((size_t)b * C + c) * L;
        for (int l = tid; l < L; l += 256) { float v = row[l]; s += v; s2 += v * v; }
    }
#pragma unroll
    for (int off = 32; off > 0; off >>= 1) { s += __shfl_down(s, off); s2 += __shfl_down(s2, off); }
    __shared__ float ss[4], ss2[4];
    if ((tid & 63) == 0) { ss[tid >> 6] = s; ss2[tid >> 6] = s2; }
    __syncthreads();
    if (tid == 0) {
        float S = ss[0] + ss[1] + ss[2] + ss[3];
        float S2 = ss2[0] + ss2[1] + ss2[2] + ss2[3];
        float n = (float)(Bn * L);
        float m = S / n;
        float v = S2 / n - m * m;
        mean[c] = m;
        rstd[c] = rsqrtf(v + 1e-5f);
    }
}

// ---------------------------------------------------------------------------
// BN-fold transforms: w'[c,k,o] = w[o,c,k]*sc[c]; b'[o] = b[o] + sum w*sh[c].
// bnfold2: grid(128), block 256 (one block per output channel)
__global__ void bnfold2_kernel(const float* __restrict__ w2, const float* __restrict__ b2,
                               const float* __restrict__ m1, const float* __restrict__ r1,
                               const float* __restrict__ g1, const float* __restrict__ be1,
                               float* __restrict__ w2t, float* __restrict__ b2t) {
    const int o = blockIdx.x, tid = threadIdx.x;
    float part = 0.f;
    for (int idx = tid; idx < WCH * 3; idx += 256) {
        const int c = idx / 3;
        const float sc = r1[c] * g1[c];
        const float sh = be1[c] - m1[c] * sc;
        const float wv = w2[(size_t)o * (WCH * 3) + idx];
        w2t[(size_t)idx * 128 + o] = wv * sc;
        part += wv * sh;
    }
#pragma unroll
    for (int off = 32; off > 0; off >>= 1) part += __shfl_down(part, off);
    __shared__ float red[4];
    if ((tid & 63) == 0) red[tid >> 6] = part;
    __syncthreads();
    if (tid == 0) b2t[o] = b2[o] + red[0] + red[1] + red[2] + red[3];
}

// bnfold3: grid(32), block 256
__global__ void bnfold3_kernel(const float* __restrict__ w3, const float* __restrict__ b3,
                               const float* __restrict__ m2, const float* __restrict__ r2,
                               const float* __restrict__ g2, const float* __restrict__ be2,
                               float* __restrict__ w3t, float* __restrict__ b3t) {
    const int o = blockIdx.x, tid = threadIdx.x;
    float part = 0.f;
    for (int idx = tid; idx < 128 * 5; idx += 256) {
        const int c = idx / 5;
        const float sc = r2[c] * g2[c];
        const float sh = be2[c] - m2[c] * sc;
        const float wv = w3[(size_t)o * 640 + idx];
        w3t[(size_t)idx * 32 + o] = wv * sc;
        part += wv * sh;
    }
#pragma unroll
    for (int off = 32; off > 0; off >>= 1) part += __shfl_down(part, off);
    __shared__ float red[4];
    if ((tid & 63) == 0) red[tid >> 6] = part;
    __syncthreads();
    if (tid == 0) b3t[o] = b3[o] + red[0] + red[1] + red[2] + red[3];
}

// bnfold4: grid(16), block 128. Block 0 also emits BN3 affine (sc,sh) for dwt.
__global__ void bnfold4_kernel(const float* __restrict__ w4, const float* __restrict__ b4,
                               const float* __restrict__ m3, const float* __restrict__ r3,
                               const float* __restrict__ g3, const float* __restrict__ be3,
                               float* __restrict__ w4t, float* __restrict__ b4t,
                               float* __restrict__ bnp3) {
    const int o = blockIdx.x, tid = threadIdx.x;
    float part = 0.f;
    if (tid < 96) {
        const int c = tid / 3;
        const float sc = r3[c] * g3[c];
        const float sh = be3[c] - m3[c] * sc;
        const float wv = w4[(size_t)o * 96 + tid];
        w4t[(size_t)tid * 16 + o] = wv * sc;
        part = wv * sh;
    }
    if (o == 0 && tid >= 96) {
        const int ch = tid - 96;
        const float sc = r3[ch] * g3[ch];
        bnp3[ch] = sc;
        bnp3[32 + ch] = be3[ch] - m3[ch] * sc;
    }
#pragma unroll
    for (int off = 32; off > 0; off >>= 1) part += __shfl_down(part, off);
    __shared__ float red[2];
    if ((tid & 63) == 0) red[tid >> 6] = part;
    __syncthreads();
    if (tid == 0) b4t[o] = b4[o] + red[0] + red[1];
}

// ---------------------------------------------------------------------------
// conv2 (BN1 folded): wave_raw [32,768,518] -> relu -> y2 [32,128,516], k=3.
// 16 output channels per thread; weights [c][k][o] -> uniform s_load streams.
// grid(32 b, 3 t, 8 o) — blockIdx.x = b so b%8 pins each batch to one XCD L2.
__global__ __launch_bounds__(256) void conv2_kernel(
        const float* __restrict__ in, const float* __restrict__ wt,
        const float* __restrict__ bt, float* __restrict__ out) {
    const int b  = blockIdx.x;
    const int t  = blockIdx.y * 256 + threadIdx.x;
    const int o0 = blockIdx.z * 16;
    if (t >= L2_) return;
    float acc[16];
#pragma unroll
    for (int j = 0; j < 16; ++j) acc[j] = bt[o0 + j];
    const float* inb = in + (size_t)b * WCH * T_ + t;
    for (int c = 0; c < WCH; ++c) {
        const float x0 = inb[c * T_], x1 = inb[c * T_ + 1], x2 = inb[c * T_ + 2];
        const float* wc = wt + (size_t)c * 384 + o0;   // [c][k][o], k-stride 128
#pragma unroll
        for (int j = 0; j < 16; ++j)
            acc[j] = fmaf(x0, wc[j], fmaf(x1, wc[128 + j], fmaf(x2, wc[256 + j], acc[j])));
    }
    const size_t ob = ((size_t)b * 128 + o0) * L2_ + t;
#pragma unroll
    for (int j = 0; j < 16; ++j) out[ob + (size_t)j * L2_] = fmaxf(acc[j], 0.f);
}

// conv3 (BN2 folded): y2_raw [32,128,516] -> relu -> y3 [32,32,512], k=5.
// grid(32 b, 2 t, 4 o), 8 channels per thread, weights [c][k][o].
__global__ __launch_bounds__(256) void conv3_kernel(
        const float* __restrict__ in, const float* __restrict__ wt,
        const float* __restrict__ bt, float* __restrict__ out) {
    const int b  = blockIdx.x;
    const int t  = blockIdx.y * 256 + threadIdx.x;   // < 512 always
    const int o0 = blockIdx.z * 8;
    float acc[8];
#pragma unroll
    for (int j = 0; j < 8; ++j) acc[j] = bt[o0 + j];
    const float* inb = in + (size_t)b * 128 * L2_ + t;
    for (int c = 0; c < 128; ++c) {
        const float x0 = inb[c * L2_], x1 = inb[c * L2_ + 1], x2 = inb[c * L2_ + 2];
        const float x3 = inb[c * L2_ + 3], x4 = inb[c * L2_ + 4];
        const float* wc = wt + (size_t)c * 160 + o0;   // [c][k][o], k-stride 32
#pragma unroll
        for (int j = 0; j < 8; ++j) {
            float a = fmaf(x0, wc[j], acc[j]);
            a = fmaf(x1, wc[32 + j], a);
            a = fmaf(x2, wc[64 + j], a);
            a = fmaf(x3, wc[96 + j], a);
            acc[j] = fmaf(x4, wc[128 + j], a);
        }
    }
    const size_t ob = ((size_t)b * 32 + o0) * L3_ + t;
#pragma unroll
    for (int j = 0; j < 8; ++j) out[ob + (size_t)j * L3_] = fmaxf(acc[j], 0.f);
}

// conv4 (BN3 folded): y3_raw [32,32,512] -> relu -> y4 [32,16,510], k=3.
// All 16 output channels per thread. grid(32 b, 2 t), block 256.
__global__ __launch_bounds__(256) void conv4_kernel(
        const float* __restrict__ in, const float* __restrict__ wt,
        const float* __restrict__ bt, float* __restrict__ out) {
    const int b = blockIdx.x;
    const int t = blockIdx.y * 256 + threadIdx.x;
    if (t >= L4_) return;
    float acc[16];
#pragma unroll
    for (int j = 0; j < 16; ++j) acc[j] = bt[j];
    const float* inb = in + (size_t)b * 32 * L3_ + t;
    for (int c = 0; c < 32; ++c) {
        const float x0 = inb[c * L3_], x1 = inb[c * L3_ + 1], x2 = inb[c * L3_ + 2];
        const float* wc = wt + (size_t)c * 48;         // [c][k][o], k-stride 16
#pragma unroll
        for (int j = 0; j < 16; ++j)
            acc[j] = fmaf(x0, wc[j], fmaf(x1, wc[16 + j], fmaf(x2, wc[32 + j], acc[j])));
    }
    const size_t ob = ((size_t)b * 16) * L4_ + t;
#pragma unroll
    for (int j = 0; j < 16; ++j) out[ob + (size_t)j * L4_] = fmaxf(acc[j], 0.f);
}

// Fused BN3(inline) + DWT bands + conv5 + relu -> y5 [32,16,510]. grid(32), block 512
__global__ __launch_bounds__(512) void dwt_conv5_kernel(const float* __restrict__ y3,
                                                        const float* __restrict__ w5,
                                                        const float* __restrict__ b5,
                                                        const float* __restrict__ bnp3,
                                                        float* __restrict__ y5) {
    const int b = blockIdx.x, l = threadIdx.x;  // l in [0,512)
    __shared__ float cm[L3_];
    __shared__ float bands[5][L3_];
    __shared__ float w5s[240];
    __shared__ float b5s[16];
    __shared__ float sc3s[32], sh3s[32];
    if (l < 240) w5s[l] = w5[l];
    if (l < 16) b5s[l] = b5[l];
    if (l >= 256 && l < 288) sc3s[l - 256] = bnp3[l - 256];
    if (l >= 288 && l < 320) sh3s[l - 288] = bnp3[32 + (l - 288)];
    __syncthreads();
    float s = 0.f, shs = 0.f;
    for (int ch = 0; ch < 32; ++ch) {
        s = fmaf(y3[((size_t)b * 32 + ch) * L3_ + l], sc3s[ch], s);
        shs += sh3s[ch];
    }
    cm[l] = (s + shs) * (1.f / 32.f);
    __syncthreads();
    const float s1 = 0.70710678118654752440f;
    const float s2c = 0.5f;
    const float s3 = 0.35355339059327378f;
    const float s4 = 0.25f;
    const int b16 = l & ~15, b8 = l & ~7, b4v = l & ~3, b2v = l & ~1;
    float sa = 0.f, sb = 0.f;
#pragma unroll
    for (int i = 0; i < 8; ++i) { sa += cm[b16 + i]; sb += cm[b16 + 8 + i]; }
    bands[0][l] = (sa + sb) * s4;
    bands[1][l] = (sa - sb) * s4;
    float ta = 0.f, tb = 0.f;
#pragma unroll
    for (int i = 0; i < 4; ++i) { ta += cm[b8 + i]; tb += cm[b8 + 4 + i]; }
    bands[2][l] = (ta - tb) * s3;
    bands[3][l] = (cm[b4v] + cm[b4v + 1] - cm[b4v + 2] - cm[b4v + 3]) * s2c;
    bands[4][l] = (cm[b2v] - cm[b2v + 1]) * s1;
    __syncthreads();
    if (l < L4_) {
        float in3[5][3];
#pragma unroll
        for (int c = 0; c < 5; ++c) {
            in3[c][0] = bands[c][l]; in3[c][1] = bands[c][l + 1]; in3[c][2] = bands[c][l + 2];
        }
#pragma unroll
        for (int o = 0; o < 16; ++o) {
            float acc = b5s[o];
#pragma unroll
            for (int c = 0; c < 5; ++c) {
                const float* wp = &w5s[(o * 5 + c) * 3];
                acc += in3[c][0] * wp[0] + in3[c][1] * wp[1] + in3[c][2] * wp[2];
            }
            y5[((size_t)b * 16 + o) * L4_ + l] = fmaxf(acc, 0.f);
        }
    }
}

// Merged BN4-stats + BN5-stats + pooling + FC. grid(1), block 512.
__global__ __launch_bounds__(512) void tail_final_kernel(
        const float* __restrict__ y4, const float* __restrict__ y5,
        const float* __restrict__ g4, const float* __restrict__ be4,
        const float* __restrict__ g5, const float* __restrict__ be5,
        const float* __restrict__ fcw, const float* __restrict__ fcb,
        float* __restrict__ out) {
    const int p = threadIdx.x;           // 0..511
    const int b = p >> 4, ch = p & 15;
    const float2* p4 = (const float2*)(y4 + ((size_t)(b * 16 + ch)) * L4_);
    const float2* p5 = (const float2*)(y5 + ((size_t)(b * 16 + ch)) * L4_);
    float s4 = 0.f, q4 = 0.f, s5 = 0.f, q5 = 0.f;
    for (int i = 0; i < L4_ / 2; ++i) {
        float2 a = p4[i], bb2 = p5[i];
        s4 += a.x + a.y;  q4 += a.x * a.x + a.y * a.y;
        s5 += bb2.x + bb2.y; q5 += bb2.x * bb2.x + bb2.y * bb2.y;
    }
    __shared__ float S4[512], Q4[512], S5[512], Q5[512];
    __shared__ float M4[16], R4[16], M5[16], R5[16];
    __shared__ float pool[B_][16];
    S4[p] = s4; Q4[p] = q4; S5[p] = s5; Q5[p] = q5;
    __syncthreads();
    if (p < 16) {
        float ts = 0.f, tq = 0.f, us = 0.f, uq = 0.f;
        for (int bb = 0; bb < B_; ++bb) {
            ts += S4[bb * 16 + p]; tq += Q4[bb * 16 + p];
            us += S5[bb * 16 + p]; uq += Q5[bb * 16 + p];
        }
        const float n = (float)(B_ * L4_);
        float m = ts / n; M4[p] = m; R4[p] = rsqrtf(tq / n - m * m + 1e-5f);
        m = us / n;       M5[p] = m; R5[p] = rsqrtf(uq / n - m * m + 1e-5f);
    }
    __syncthreads();
    {
        const float mm4 = s4 / (float)L4_, mm5 = s5 / (float)L4_;
        const float v4 = (mm4 - M4[ch]) * R4[ch] * g4[ch] + be4[ch];
        const float v5 = (mm5 - M5[ch]) * R5[ch] * g5[ch] + be5[ch];
        pool[b][ch] = 0.5f * (v4 + v5);
    }
    __syncthreads();
    if (p < B_ * 10) {
        const int bb = p / 10, row = p - bb * 10;
        float a = fcb[row];
#pragma unroll
        for (int c = 0; c < 16; ++c) a += pool[bb][c] * fcw[row * 16 + c];
        out[bb * 10 + row] = a;
    }
}

// ---------------------------------------------------------------------------
extern "C" void kernel_launch(void* const* d_in, const int* in_sizes, int n_in,
                              void* d_out, int out_size, void* d_ws, size_t ws_size,
                              hipStream_t stream) {
    (void)in_sizes; (void)n_in; (void)out_size; (void)ws_size;
    const float* x   = (const float*)d_in[0];
    const float* wif = (const float*)d_in[1];
    const float* whf = (const float*)d_in[2];
    const float* bf  = (const float*)d_in[3];
    const float* wir = (const float*)d_in[4];
    const float* whr = (const float*)d_in[5];
    const float* br  = (const float*)d_in[6];
    const float* bw  = (const float*)d_in[7];
    const float* bb  = (const float*)d_in[8];
    const float* g1  = (const float*)d_in[9];  const float* be1 = (const float*)d_in[10];
    const float* g2  = (const float*)d_in[11]; const float* be2 = (const float*)d_in[12];
    const float* g3  = (const float*)d_in[13]; const float* be3 = (const float*)d_in[14];
    const float* g4  = (const float*)d_in[15]; const float* be4 = (const float*)d_in[16];
    const float* g5  = (const float*)d_in[17]; const float* be5 = (const float*)d_in[18];
    const float* w2  = (const float*)d_in[19]; const float* b2  = (const float*)d_in[20];
    const float* w3  = (const float*)d_in[21]; const float* b3  = (const float*)d_in[22];
    const float* w4  = (const float*)d_in[23]; const float* b4  = (const float*)d_in[24];
    const float* w5  = (const float*)d_in[25]; const float* b5  = (const float*)d_in[26];
    const float* fcw = (const float*)d_in[27]; const float* fcb = (const float*)d_in[28];
    float* out = (float*)d_out;
    float* ws  = (float*)d_ws;

    // Workspace layout (floats). xg region is reused by `wave` after the LSTM.
    float* xg_f  = ws;                       //  4,243,456
    float* xg_r  = ws + 4243456;             //  4,243,456
    float* wave  = ws;                       // 12,730,368 (reuses xg region)
    float* X     = ws + 12730368;            //  2,121,728 (dead after wave_kernel)
    float* y2    = ws + 14852096;            //  2,113,536
    float* y3    = ws + 16965632;            //    524,288
    float* y4    = ws + 17489920;            //    261,120
    float* y5    = ws + 17751040;            //    261,120
    float* stats = ws + 18012160;            //      1,536 (BN1 s/s2)
    float* m1 = ws + 18013696; float* r1 = m1 + 768;
    float* m2 = r1 + 768;      float* r2 = m2 + 128;
    float* m3 = r2 + 128;      float* r3 = m3 + 32;   // ends ~18,015,296 floats
    // Folded weights live in the dead X region (X only read by wave_kernel):
    float* w2t  = X;                  // 294,912
    float* b2t  = X + 294912;         //     128
    float* w3t  = X + 295040;         //  20,480
    float* b3t  = X + 315520;         //      32
    float* w4t  = X + 315552;         //   1,536
    float* b4t  = X + 317088;         //      16
    float* bnp3 = X + 317104;         //      64  (BN3 sc|sh for dwt)

    // 1) input projections + zero BN1 stats
    xg_kernel<<<dim3(65, 32), 256, 0, stream>>>(x, wif, bf, wir, br, xg_f, xg_r, stats);
    // 2) bidirectional LSTM recurrence -> X
    lstm_kernel<<<dim3(64), 128, 0, stream>>>(xg_f, xg_r, whf, whr, X);
    // 3) wave module -> wave (raw), fused BN1 partial stats
    wave_kernel<<<dim3(3, CCH, B_), 256, 0, stream>>>(X, bw, bb, wave, stats);
    bn1_finalize_kernel<<<dim3(1), 768, 0, stream>>>(stats, m1, r1);
    // 4) fold BN1 into conv2 weights; conv2 on raw wave
    bnfold2_kernel<<<dim3(128), 256, 0, stream>>>(w2, b2, m1, r1, g1, be1, w2t, b2t);
    conv2_kernel<<<dim3(32, 3, 8), 256, 0, stream>>>(wave, w2t, b2t, y2);
    // 5) BN2 stats on raw y2; fold into conv3; conv3
    bn_stats_kernel<<<dim3(128), 256, 0, stream>>>(y2, B_, 128, L2_, m2, r2);
    bnfold3_kernel<<<dim3(32), 256, 0, stream>>>(w3, b3, m2, r2, g2, be2, w3t, b3t);
    conv3_kernel<<<dim3(32, 2, 4), 256, 0, stream>>>(y2, w3t, b3t, y3);
    // 6) BN3 stats on raw y3; fold into conv4 + dwt affine
    bn_stats_kernel<<<dim3(32), 256, 0, stream>>>(y3, B_, 32, L3_, m3, r3);
    bnfold4_kernel<<<dim3(16), 128, 0, stream>>>(w4, b4, m3, r3, g3, be3, w4t, b4t, bnp3);
    // 7) conv4 on raw y3 (folded)
    conv4_kernel<<<dim3(32, 2), 256, 0, stream>>>(y3, w4t, b4t, y4);
    // 8) fused BN3-affine + DWT + conv5
    dwt_conv5_kernel<<<dim3(B_), 512, 0, stream>>>(y3, w5, b5, bnp3, y5);
    // 9) merged BN4/BN5 stats + pooling(+affine) + FC
    tail_final_kernel<<<dim3(1), 512, 0, stream>>>(y4, y5, g4, be4, g5, be5, fcw, fcb, out);
}